// Round 5
// baseline (577.340 us; speedup 1.0000x reference)
//
#include <hip/hip_runtime.h>
#include <math.h>

#define NEGSLOPE 0.2f

__device__ __forceinline__ float lrelu(float x) { return x > 0.f ? x : NEGSLOPE * x; }

// ---------------- CSR build ----------------
__global__ void k_count(const int* __restrict__ tgt, int* __restrict__ deg, int e) {
    int i = blockIdx.x * 256 + threadIdx.x;
    if (i < e) atomicAdd(&deg[tgt[i]], 1);
}
// block scans 4096 elements (256 threads x 16); +1 per element folds in the self-loop
__global__ __launch_bounds__(256) void k_scanA(const int* __restrict__ deg, int* __restrict__ rowptr,
                                               int* __restrict__ bsums, int n) {
    __shared__ int s[256];
    int t = threadIdx.x;
    int base = blockIdx.x * 4096 + t * 16;
    int pre[16];
    int sum = 0;
    for (int i = 0; i < 16; ++i) {
        int idx = base + i;
        int v = (idx < n) ? (deg[idx] + 1) : 0;
        pre[i] = sum;
        sum += v;
    }
    s[t] = sum;
    __syncthreads();
    for (int off = 1; off < 256; off <<= 1) {
        int v = (t >= off) ? s[t - off] : 0;
        __syncthreads();
        s[t] += v;
        __syncthreads();
    }
    int tbase = s[t] - sum;   // exclusive base for this thread within block
    for (int i = 0; i < 16; ++i) {
        int idx = base + i;
        if (idx < n) rowptr[idx] = tbase + pre[i];
    }
    if (t == 0) bsums[blockIdx.x] = s[255];
}
__global__ void k_scanB(int* __restrict__ bsums, int* __restrict__ rowptr, int nblk, int n) {
    if (threadIdx.x == 0 && blockIdx.x == 0) {
        int run = 0;
        for (int i = 0; i < nblk; ++i) { int v = bsums[i]; bsums[i] = run; run += v; }
        rowptr[n] = run;   // Etot
    }
}
// finalize rowptr, seed self-loop edge, init scatter cursor — one pass
__global__ void k_scanC(int* __restrict__ rowptr, const int* __restrict__ bsums,
                        int* __restrict__ edst, int* __restrict__ cursor, int n) {
    int i = blockIdx.x * 256 + threadIdx.x;
    if (i < n) {
        int rp = rowptr[i] + bsums[i >> 12];   // 4096 per scan block
        rowptr[i] = rp;
        edst[rp] = i;                          // self loop first in each row
        cursor[i] = rp + 1;
    }
}
__global__ void k_scatter(const int* __restrict__ src, const int* __restrict__ tgt,
                          int* __restrict__ cursor, int* __restrict__ edst, int e) {
    int i = blockIdx.x * 256 + threadIdx.x;
    if (i < e) { int p = atomicAdd(&cursor[tgt[i]], 1); edst[p] = src[i]; }
}

// ---------------- fused fp32 GEMM: out0 = A@W0, out1 = A@W1 (W: [128,KOUT]) ----
// 64-row block; A tile staged ONCE in LDS, reused across 2*KOUT/64 column tiles.
// Ws staged in half-K (64-row) tiles: LDS = 33.8+17.4 = 50 KB -> 3 blocks/CU.
template<int KOUT>
__global__ __launch_bounds__(256) void k_gemm_fused(const float* __restrict__ Ain,
        const float* __restrict__ W0, const float* __restrict__ W1,
        float* __restrict__ out0, float* __restrict__ out1, int n) {
    constexpr int CTW = KOUT / 64;           // column tiles per weight matrix
    __shared__ float As[64][132];            // stride 132: 16B-aligned rows, bank-stagger
    __shared__ float Ws[64][68];             // half-K tile of W
    int t = threadIdx.x;
    int row0 = blockIdx.x * 64;
    for (int i = 0; i < 8; ++i) {
        int idx = t + 256 * i;
        int r = idx >> 5, kq = idx & 31;
        float4 v = make_float4(0.f, 0.f, 0.f, 0.f);
        int gr = row0 + r;
        if (gr < n) v = *(const float4*)(Ain + (size_t)gr * 128 + 4 * kq);
        *(float4*)&As[r][4 * kq] = v;
    }
    int tx = t & 15, ty = t >> 4;
    int r0 = ty * 4, cl = tx * 4;
    for (int ct = 0; ct < 2 * CTW; ++ct) {
        const float* W = (ct < CTW) ? W0 : W1;
        float* out = (ct < CTW) ? out0 : out1;
        int c0 = (ct & (CTW - 1)) * 64;
        float acc[4][4] = {};
        for (int kh = 0; kh < 2; ++kh) {
            __syncthreads();                 // As ready (first) / Ws drained (later)
            for (int i = 0; i < 4; ++i) {
                int idx = t + 256 * i;
                int k = idx >> 4, cq = idx & 15;
                *(float4*)&Ws[k][4 * cq] =
                    *(const float4*)(W + (size_t)(kh * 64 + k) * KOUT + c0 + 4 * cq);
            }
            __syncthreads();
            int kb = kh * 64;
#pragma unroll 4
            for (int k = 0; k < 64; k += 4) {
                float a_[4][4], w_[4][4];
#pragma unroll
                for (int j = 0; j < 4; ++j) *(float4*)a_[j] = *(const float4*)&As[r0 + j][kb + k];
#pragma unroll
                for (int kk = 0; kk < 4; ++kk) *(float4*)w_[kk] = *(const float4*)&Ws[k + kk][cl];
#pragma unroll
                for (int kk = 0; kk < 4; ++kk)
#pragma unroll
                    for (int j = 0; j < 4; ++j) {
                        acc[j][0] += a_[j][kk] * w_[kk][0];
                        acc[j][1] += a_[j][kk] * w_[kk][1];
                        acc[j][2] += a_[j][kk] * w_[kk][2];
                        acc[j][3] += a_[j][kk] * w_[kk][3];
                    }
            }
        }
        for (int j = 0; j < 4; ++j) {
            int gr = row0 + r0 + j;
            if (gr < n)
                *(float4*)(out + (size_t)gr * KOUT + c0 + cl) =
                    make_float4(acc[j][0], acc[j][1], acc[j][2], acc[j][3]);
        }
    }
}

// ---------------- GATv2 aggregation: 4 nodes per wave, 16 lanes per node ------
// Lane holds VEC = F/16 channels. Head spans L = C/VEC lanes (4 for H=4, 16 for H=1).
// Edge loop unrolled x4: 16 independent row gathers in flight per wave.
// No max-subtraction (scores bounded -> exp(p)/sum exp(p) identical to ref softmax).
template<int H, int C>
__global__ __launch_bounds__(256) void k_agg(const float* __restrict__ xl, const float* __restrict__ xr,
                                             const float* __restrict__ att, const float* __restrict__ bias,
                                             const int* __restrict__ rowptr, const int* __restrict__ edst,
                                             float* __restrict__ yout, int n) {
    constexpr int F = H * C;
    constexpr int VEC = F / 16;      // 8 (F=128) or 4 (F=64)
    constexpr int L = C / VEC;       // lanes per head: 4 or 16
    int lane = threadIdx.x & 63;
    int wave = threadIdx.x >> 6;
    int s = lane & 15;               // sublane within node group
    int node = blockIdx.x * 16 + wave * 4 + (lane >> 4);
    bool valid = node < n;
    int nodeSafe = valid ? node : 0;
    int ch = s * VEC;

    float u[VEC], av[VEC], acc[VEC];
#pragma unroll
    for (int j = 0; j < VEC; ++j) {
        u[j] = xr[(size_t)nodeSafe * F + ch + j];
        av[j] = att[ch + j];
        acc[j] = 0.f;
    }
    int e0 = rowptr[nodeSafe];
    int deg = valid ? (rowptr[nodeSafe + 1] - e0) : 0;
    int maxdeg = deg;                // wave-uniform max degree over the 4 node groups
    maxdeg = max(maxdeg, __shfl_xor(maxdeg, 16));
    maxdeg = max(maxdeg, __shfl_xor(maxdeg, 32));
    float ssum = 0.f;

    auto loadrow = [&](int src, float* v) {
        const float* p = xl + (size_t)src * F + ch;
        *(float4*)v = *(const float4*)p;
        if constexpr (VEC == 8) *(float4*)(v + 4) = *(const float4*)(p + 4);
    };
    auto dot = [&](const float* v) {
        float p = 0.f;
#pragma unroll
        for (int j = 0; j < VEC; ++j) p += lrelu(v[j] + u[j]) * av[j];
        return p;
    };
    auto accum = [&](float w, const float* v) {
        ssum += w;
#pragma unroll
        for (int j = 0; j < VEC; ++j) acc[j] += w * v[j];
    };

    for (int base = 0; base < maxdeg; base += 16) {
        int cnt = deg - base;                        // group-uniform
        if (cnt > 16) cnt = 16;
        int idxreg = (s < cnt) ? edst[e0 + base + s] : nodeSafe;
        int mcnt = cnt;                              // wave max for this chunk
        mcnt = max(mcnt, __shfl_xor(mcnt, 16));
        mcnt = max(mcnt, __shfl_xor(mcnt, 32));
        int gbase = lane & 48;                       // group<<4
        int i = 0;
        for (; i + 4 <= mcnt; i += 4) {
            int s0 = __shfl(idxreg, gbase + i);
            int s1 = __shfl(idxreg, gbase + i + 1);
            int s2 = __shfl(idxreg, gbase + i + 2);
            int s3 = __shfl(idxreg, gbase + i + 3);
            float v0[VEC], v1[VEC], v2[VEC], v3[VEC];
            loadrow(s0, v0); loadrow(s1, v1); loadrow(s2, v2); loadrow(s3, v3);
            float p0 = dot(v0), p1 = dot(v1), p2 = dot(v2), p3 = dot(v3);
#pragma unroll
            for (int off = 1; off < L; off <<= 1) {
                p0 += __shfl_xor(p0, off);
                p1 += __shfl_xor(p1, off);
                p2 += __shfl_xor(p2, off);
                p3 += __shfl_xor(p3, off);
            }
            float w0 = (i + 0 < cnt) ? __expf(p0) : 0.f;
            float w1 = (i + 1 < cnt) ? __expf(p1) : 0.f;
            float w2 = (i + 2 < cnt) ? __expf(p2) : 0.f;
            float w3 = (i + 3 < cnt) ? __expf(p3) : 0.f;
            accum(w0, v0); accum(w1, v1); accum(w2, v2); accum(w3, v3);
        }
        for (; i < mcnt; ++i) {
            int s0 = __shfl(idxreg, gbase + i);
            float v[VEC];
            loadrow(s0, v);
            float p = dot(v);
#pragma unroll
            for (int off = 1; off < L; off <<= 1) p += __shfl_xor(p, off);
            float w = (i < cnt) ? __expf(p) : 0.f;
            accum(w, v);
        }
    }
    if (valid) {
        float inv = 1.f / ssum;
        float o[VEC];
#pragma unroll
        for (int j = 0; j < VEC; ++j) o[j] = lrelu(acc[j] * inv + bias[ch + j]);
        float* p = yout + (size_t)node * F + ch;
        *(float4*)p = *(float4*)o;
        if constexpr (VEC == 8) *(float4*)(p + 4) = *(float4*)(o + 4);
    }
}

// ---------------- global mean pool (batch sorted -> binary-search ranges) ----------------
__global__ __launch_bounds__(256) void k_pool(const float* __restrict__ y, const int* __restrict__ batch,
                                              float* __restrict__ out, int n) {
    __shared__ float sdata[256];
    __shared__ int range[2];
    int g = blockIdx.x;
    int t = threadIdx.x;
    if (t == 0) {
        int lo = 0, hi = n;
        while (lo < hi) { int mid = (lo + hi) >> 1; if (batch[mid] < g) lo = mid + 1; else hi = mid; }
        range[0] = lo;
        hi = n;
        while (lo < hi) { int mid = (lo + hi) >> 1; if (batch[mid] < g + 1) lo = mid + 1; else hi = mid; }
        range[1] = lo;
    }
    __syncthreads();
    int start = range[0], end = range[1];
    int ch = t & 63, sub = t >> 6;
    float acc = 0.f;
    for (int node = start + sub; node < end; node += 4)
        acc += y[(size_t)node * 64 + ch];
    sdata[t] = acc;
    __syncthreads();
    if (t < 128) sdata[t] += sdata[t + 128];
    __syncthreads();
    if (t < 64) {
        float s = sdata[t] + sdata[t + 64];
        float cnt = (float)(end - start);
        out[g * 64 + t] = s / fmaxf(cnt, 1.f);
    }
}

extern "C" void kernel_launch(void* const* d_in, const int* in_sizes, int n_in,
                              void* d_out, int out_size, void* d_ws, size_t ws_size,
                              hipStream_t stream) {
    const float* x     = (const float*)d_in[0];
    const int*   ei    = (const int*)d_in[1];
    const int*   batch = (const int*)d_in[2];
    const float* Wl0 = (const float*)d_in[3];
    const float* Wr0 = (const float*)d_in[4];
    const float* att0 = (const float*)d_in[5];
    const float* b0  = (const float*)d_in[6];
    const float* Wl1 = (const float*)d_in[7];
    const float* Wr1 = (const float*)d_in[8];
    const float* att1 = (const float*)d_in[9];
    const float* b1  = (const float*)d_in[10];
    const float* Wl2 = (const float*)d_in[11];
    const float* Wr2 = (const float*)d_in[12];
    const float* att2 = (const float*)d_in[13];
    const float* b2  = (const float*)d_in[14];

    const int N = in_sizes[2];        // 50000
    const int E = in_sizes[1] / 2;    // 800000
    const int G = out_size / 64;      // 64
    const int* src = ei;
    const int* tgt = ei + E;

    // workspace layout (all 256B aligned)
    size_t off = 0;
    auto take = [&](size_t bytes) {
        void* p = (char*)d_ws + off;
        off = (off + bytes + 255) & ~(size_t)255;
        return p;
    };
    float* A    = (float*)take((size_t)N * 128 * 4);   // xl
    float* B    = (float*)take((size_t)N * 128 * 4);   // xr
    float* Cb   = (float*)take((size_t)N * 128 * 4);   // layer output / next input
    int* rowptr = (int*)take((size_t)(N + 1) * 4);
    int* tmp    = (int*)take((size_t)N * 4);           // deg, then cursor
    int* edst   = (int*)take((size_t)(E + N) * 4);
    int* bsums  = (int*)take(64 * 4);
    (void)ws_size; (void)n_in;

    const int TB = 256;
    int nblkN = (N + TB - 1) / TB;
    int nblkE = (E + TB - 1) / TB;
    int nscan = (N + 4095) / 4096;

    // --- CSR build (same topology for all layers) ---
    hipMemsetAsync(tmp, 0, (size_t)N * 4, stream);
    k_count<<<nblkE, TB, 0, stream>>>(tgt, tmp, E);
    k_scanA<<<nscan, TB, 0, stream>>>(tmp, rowptr, bsums, N);
    k_scanB<<<1, 64, 0, stream>>>(bsums, rowptr, nscan, N);
    k_scanC<<<nblkN, TB, 0, stream>>>(rowptr, bsums, edst, tmp, N);
    k_scatter<<<nblkE, TB, 0, stream>>>(src, tgt, tmp, edst, E);

    int gemmBlocks = (N + 63) / 64;
    int aggBlocks = (N + 15) / 16;

    // --- layer 0: x[N,128] -> Cb[N,128] ---
    k_gemm_fused<128><<<gemmBlocks, TB, 0, stream>>>(x, Wl0, Wr0, A, B, N);
    k_agg<4, 32><<<aggBlocks, TB, 0, stream>>>(A, B, att0, b0, rowptr, edst, Cb, N);

    // --- layer 1: Cb -> Cb ---
    k_gemm_fused<128><<<gemmBlocks, TB, 0, stream>>>(Cb, Wl1, Wr1, A, B, N);
    k_agg<4, 32><<<aggBlocks, TB, 0, stream>>>(A, B, att1, b1, rowptr, edst, Cb, N);

    // --- layer 2: Cb[N,128] -> Cb[N,64] ---
    k_gemm_fused<64><<<gemmBlocks, TB, 0, stream>>>(Cb, Wl2, Wr2, A, B, N);
    k_agg<1, 64><<<aggBlocks, TB, 0, stream>>>(A, B, att2, b2, rowptr, edst, Cb, N);

    // --- global mean pool ---
    k_pool<<<G, TB, 0, stream>>>(Cb, batch, (float*)d_out, N);
}

// Round 6
// 573.030 us; speedup vs baseline: 1.0075x; 1.0075x over previous
//
#include <hip/hip_runtime.h>
#include <math.h>

#define NEGSLOPE 0.2f

__device__ __forceinline__ float lrelu(float x) { return x > 0.f ? x : NEGSLOPE * x; }

// ---------------- CSR build ----------------
__global__ void k_count(const int* __restrict__ tgt, int* __restrict__ deg, int e) {
    int i = blockIdx.x * 256 + threadIdx.x;
    if (i < e) atomicAdd(&deg[tgt[i]], 1);
}
// block scans 4096 elements (256 threads x 16); +1 per element folds in the self-loop
__global__ __launch_bounds__(256) void k_scanA(const int* __restrict__ deg, int* __restrict__ rowptr,
                                               int* __restrict__ bsums, int n) {
    __shared__ int s[256];
    int t = threadIdx.x;
    int base = blockIdx.x * 4096 + t * 16;
    int pre[16];
    int sum = 0;
    for (int i = 0; i < 16; ++i) {
        int idx = base + i;
        int v = (idx < n) ? (deg[idx] + 1) : 0;
        pre[i] = sum;
        sum += v;
    }
    s[t] = sum;
    __syncthreads();
    for (int off = 1; off < 256; off <<= 1) {
        int v = (t >= off) ? s[t - off] : 0;
        __syncthreads();
        s[t] += v;
        __syncthreads();
    }
    int tbase = s[t] - sum;   // exclusive base for this thread within block
    for (int i = 0; i < 16; ++i) {
        int idx = base + i;
        if (idx < n) rowptr[idx] = tbase + pre[i];
    }
    if (t == 0) bsums[blockIdx.x] = s[255];
}
__global__ void k_scanB(int* __restrict__ bsums, int* __restrict__ rowptr, int nblk, int n) {
    if (threadIdx.x == 0 && blockIdx.x == 0) {
        int run = 0;
        for (int i = 0; i < nblk; ++i) { int v = bsums[i]; bsums[i] = run; run += v; }
        rowptr[n] = run;   // Etot
    }
}
// finalize rowptr, seed self-loop edge, init scatter cursor — one pass
__global__ void k_scanC(int* __restrict__ rowptr, const int* __restrict__ bsums,
                        int* __restrict__ edst, int* __restrict__ cursor, int n) {
    int i = blockIdx.x * 256 + threadIdx.x;
    if (i < n) {
        int rp = rowptr[i] + bsums[i >> 12];   // 4096 per scan block
        rowptr[i] = rp;
        edst[rp] = i;                          // self loop first in each row
        cursor[i] = rp + 1;
    }
}
__global__ void k_scatter(const int* __restrict__ src, const int* __restrict__ tgt,
                          int* __restrict__ cursor, int* __restrict__ edst, int e) {
    int i = blockIdx.x * 256 + threadIdx.x;
    if (i < e) { int p = atomicAdd(&cursor[tgt[i]], 1); edst[p] = src[i]; }
}

// ---------------- fused fp32 GEMM: out0 = A@W0, out1 = A@W1 (W: [128,KOUT]) ----
// 128x128 output tile, 8x8 micro-tile (2 FLOP per LDS byte), K chunked at 32.
// A stored k-major (transposed) in LDS so both fragments are 2x ds_read_b128/k.
// Lane map rg=lane>>3, cg=lane&7 -> compute reads <=2-way bank-aliased (free).
template<int KOUT>
__global__ __launch_bounds__(256) void k_gemm_fused(const float* __restrict__ Ain,
        const float* __restrict__ W0, const float* __restrict__ W1,
        float* __restrict__ out0, float* __restrict__ out1, int n) {
    constexpr int NCT = KOUT / 64;           // 2 passes (W0,W1) for KOUT=128; 1 merged for 64
    __shared__ float Ast[32][132];           // A chunk, k-major: Ast[k][row]
    __shared__ float Wt[32][132];            // W chunk, row-major: Wt[k][col]
    int t = threadIdx.x;
    int w = t >> 6, lane = t & 63;
    int rg = (lane >> 3) + 8 * (w & 1);      // 0..15
    int cg = (lane & 7) + 8 * (w >> 1);      // 0..15
    int r0 = rg * 8, c0 = cg * 8;
    int row0 = blockIdx.x * 128;

    for (int ct = 0; ct < NCT; ++ct) {
        float acc[8][8] = {};
        for (int kc = 0; kc < 4; ++kc) {
            int kb = kc * 32;
            __syncthreads();                 // drain prior reads before overwrite
            // stage A chunk transposed: 128 rows x 32 k
            for (int i = 0; i < 4; ++i) {
                int idx = t + 256 * i;
                int r = idx >> 3, kq = idx & 7;
                float4 v = make_float4(0.f, 0.f, 0.f, 0.f);
                int gr = row0 + r;
                if (gr < n) v = *(const float4*)(Ain + (size_t)gr * 128 + kb + 4 * kq);
                Ast[4 * kq + 0][r] = v.x; Ast[4 * kq + 1][r] = v.y;
                Ast[4 * kq + 2][r] = v.z; Ast[4 * kq + 3][r] = v.w;
            }
            // stage W chunk: 32 k x 128 cols
            for (int i = 0; i < 4; ++i) {
                int idx = t + 256 * i;
                int k = idx >> 5, cq = idx & 31;
                float4 v;
                if (KOUT == 128) {
                    const float* W = ct ? W1 : W0;
                    v = *(const float4*)(W + (size_t)(kb + k) * 128 + 4 * cq);
                } else {  // cols [0,64)=W0, [64,128)=W1
                    const float* W = (cq < 16) ? W0 : W1;
                    int c = (cq < 16) ? 4 * cq : 4 * (cq - 16);
                    v = *(const float4*)(W + (size_t)(kb + k) * 64 + c);
                }
                *(float4*)&Wt[k][4 * cq] = v;
            }
            __syncthreads();
#pragma unroll 2
            for (int k = 0; k < 32; ++k) {
                float a_[8], b_[8];
                *(float4*)&a_[0] = *(const float4*)&Ast[k][r0];
                *(float4*)&a_[4] = *(const float4*)&Ast[k][r0 + 4];
                *(float4*)&b_[0] = *(const float4*)&Wt[k][c0];
                *(float4*)&b_[4] = *(const float4*)&Wt[k][c0 + 4];
#pragma unroll
                for (int i = 0; i < 8; ++i)
#pragma unroll
                    for (int j = 0; j < 8; ++j)
                        acc[i][j] += a_[i] * b_[j];
            }
        }
        // write 8x8 micro-tile
        for (int i = 0; i < 8; ++i) {
            int gr = row0 + r0 + i;
            if (gr >= n) break;
            float* dst;
            int c;
            if (KOUT == 128) {
                dst = ct ? out1 : out0; c = c0;
            } else {
                dst = (cg < 8) ? out0 : out1; c = (cg < 8) ? c0 : c0 - 64;
            }
            *(float4*)(dst + (size_t)gr * KOUT + c)     = *(float4*)&acc[i][0];
            *(float4*)(dst + (size_t)gr * KOUT + c + 4) = *(float4*)&acc[i][4];
        }
    }
}

// ---------------- GATv2 aggregation: 4 nodes per wave, 16 lanes per node ------
// Lane holds VEC = F/16 channels. Head spans L = C/VEC lanes (4 for H=4, 16 for H=1).
// Edge loop unrolled x4: 16 independent row gathers in flight per wave.
// No max-subtraction (scores bounded -> exp(p)/sum exp(p) identical to ref softmax).
template<int H, int C>
__global__ __launch_bounds__(256) void k_agg(const float* __restrict__ xl, const float* __restrict__ xr,
                                             const float* __restrict__ att, const float* __restrict__ bias,
                                             const int* __restrict__ rowptr, const int* __restrict__ edst,
                                             float* __restrict__ yout, int n) {
    constexpr int F = H * C;
    constexpr int VEC = F / 16;      // 8 (F=128) or 4 (F=64)
    constexpr int L = C / VEC;       // lanes per head: 4 or 16
    int lane = threadIdx.x & 63;
    int wave = threadIdx.x >> 6;
    int s = lane & 15;               // sublane within node group
    int node = blockIdx.x * 16 + wave * 4 + (lane >> 4);
    bool valid = node < n;
    int nodeSafe = valid ? node : 0;
    int ch = s * VEC;

    float u[VEC], av[VEC], acc[VEC];
#pragma unroll
    for (int j = 0; j < VEC; ++j) {
        u[j] = xr[(size_t)nodeSafe * F + ch + j];
        av[j] = att[ch + j];
        acc[j] = 0.f;
    }
    int e0 = rowptr[nodeSafe];
    int deg = valid ? (rowptr[nodeSafe + 1] - e0) : 0;
    int maxdeg = deg;                // wave-uniform max degree over the 4 node groups
    maxdeg = max(maxdeg, __shfl_xor(maxdeg, 16));
    maxdeg = max(maxdeg, __shfl_xor(maxdeg, 32));
    float ssum = 0.f;

    auto loadrow = [&](int src, float* v) {
        const float* p = xl + (size_t)src * F + ch;
        *(float4*)v = *(const float4*)p;
        if constexpr (VEC == 8) *(float4*)(v + 4) = *(const float4*)(p + 4);
    };
    auto dot = [&](const float* v) {
        float p = 0.f;
#pragma unroll
        for (int j = 0; j < VEC; ++j) p += lrelu(v[j] + u[j]) * av[j];
        return p;
    };
    auto accum = [&](float w, const float* v) {
        ssum += w;
#pragma unroll
        for (int j = 0; j < VEC; ++j) acc[j] += w * v[j];
    };

    for (int base = 0; base < maxdeg; base += 16) {
        int cnt = deg - base;                        // group-uniform
        if (cnt > 16) cnt = 16;
        int idxreg = (s < cnt) ? edst[e0 + base + s] : nodeSafe;
        int mcnt = cnt;                              // wave max for this chunk
        mcnt = max(mcnt, __shfl_xor(mcnt, 16));
        mcnt = max(mcnt, __shfl_xor(mcnt, 32));
        int gbase = lane & 48;                       // group<<4
        int i = 0;
        for (; i + 4 <= mcnt; i += 4) {
            int s0 = __shfl(idxreg, gbase + i);
            int s1 = __shfl(idxreg, gbase + i + 1);
            int s2 = __shfl(idxreg, gbase + i + 2);
            int s3 = __shfl(idxreg, gbase + i + 3);
            float v0[VEC], v1[VEC], v2[VEC], v3[VEC];
            loadrow(s0, v0); loadrow(s1, v1); loadrow(s2, v2); loadrow(s3, v3);
            float p0 = dot(v0), p1 = dot(v1), p2 = dot(v2), p3 = dot(v3);
#pragma unroll
            for (int off = 1; off < L; off <<= 1) {
                p0 += __shfl_xor(p0, off);
                p1 += __shfl_xor(p1, off);
                p2 += __shfl_xor(p2, off);
                p3 += __shfl_xor(p3, off);
            }
            float w0 = (i + 0 < cnt) ? __expf(p0) : 0.f;
            float w1 = (i + 1 < cnt) ? __expf(p1) : 0.f;
            float w2 = (i + 2 < cnt) ? __expf(p2) : 0.f;
            float w3 = (i + 3 < cnt) ? __expf(p3) : 0.f;
            accum(w0, v0); accum(w1, v1); accum(w2, v2); accum(w3, v3);
        }
        for (; i < mcnt; ++i) {
            int s0 = __shfl(idxreg, gbase + i);
            float v[VEC];
            loadrow(s0, v);
            float p = dot(v);
#pragma unroll
            for (int off = 1; off < L; off <<= 1) p += __shfl_xor(p, off);
            float w = (i < cnt) ? __expf(p) : 0.f;
            accum(w, v);
        }
    }
    if (valid) {
        float inv = 1.f / ssum;
        float o[VEC];
#pragma unroll
        for (int j = 0; j < VEC; ++j) o[j] = lrelu(acc[j] * inv + bias[ch + j]);
        float* p = yout + (size_t)node * F + ch;
        *(float4*)p = *(float4*)o;
        if constexpr (VEC == 8) *(float4*)(p + 4) = *(float4*)(o + 4);
    }
}

// ---------------- global mean pool (batch sorted -> binary-search ranges) ----------------
__global__ __launch_bounds__(256) void k_pool(const float* __restrict__ y, const int* __restrict__ batch,
                                              float* __restrict__ out, int n) {
    __shared__ float sdata[256];
    __shared__ int range[2];
    int g = blockIdx.x;
    int t = threadIdx.x;
    if (t == 0) {
        int lo = 0, hi = n;
        while (lo < hi) { int mid = (lo + hi) >> 1; if (batch[mid] < g) lo = mid + 1; else hi = mid; }
        range[0] = lo;
        hi = n;
        while (lo < hi) { int mid = (lo + hi) >> 1; if (batch[mid] < g + 1) lo = mid + 1; else hi = mid; }
        range[1] = lo;
    }
    __syncthreads();
    int start = range[0], end = range[1];
    int ch = t & 63, sub = t >> 6;
    float acc = 0.f;
    for (int node = start + sub; node < end; node += 4)
        acc += y[(size_t)node * 64 + ch];
    sdata[t] = acc;
    __syncthreads();
    if (t < 128) sdata[t] += sdata[t + 128];
    __syncthreads();
    if (t < 64) {
        float s = sdata[t] + sdata[t + 64];
        float cnt = (float)(end - start);
        out[g * 64 + t] = s / fmaxf(cnt, 1.f);
    }
}

extern "C" void kernel_launch(void* const* d_in, const int* in_sizes, int n_in,
                              void* d_out, int out_size, void* d_ws, size_t ws_size,
                              hipStream_t stream) {
    const float* x     = (const float*)d_in[0];
    const int*   ei    = (const int*)d_in[1];
    const int*   batch = (const int*)d_in[2];
    const float* Wl0 = (const float*)d_in[3];
    const float* Wr0 = (const float*)d_in[4];
    const float* att0 = (const float*)d_in[5];
    const float* b0  = (const float*)d_in[6];
    const float* Wl1 = (const float*)d_in[7];
    const float* Wr1 = (const float*)d_in[8];
    const float* att1 = (const float*)d_in[9];
    const float* b1  = (const float*)d_in[10];
    const float* Wl2 = (const float*)d_in[11];
    const float* Wr2 = (const float*)d_in[12];
    const float* att2 = (const float*)d_in[13];
    const float* b2  = (const float*)d_in[14];

    const int N = in_sizes[2];        // 50000
    const int E = in_sizes[1] / 2;    // 800000
    const int G = out_size / 64;      // 64
    const int* src = ei;
    const int* tgt = ei + E;

    // workspace layout (all 256B aligned)
    size_t off = 0;
    auto take = [&](size_t bytes) {
        void* p = (char*)d_ws + off;
        off = (off + bytes + 255) & ~(size_t)255;
        return p;
    };
    float* A    = (float*)take((size_t)N * 128 * 4);   // xl
    float* B    = (float*)take((size_t)N * 128 * 4);   // xr
    float* Cb   = (float*)take((size_t)N * 128 * 4);   // layer output / next input
    int* rowptr = (int*)take((size_t)(N + 1) * 4);
    int* tmp    = (int*)take((size_t)N * 4);           // deg, then cursor
    int* edst   = (int*)take((size_t)(E + N) * 4);
    int* bsums  = (int*)take(64 * 4);
    (void)ws_size; (void)n_in;

    const int TB = 256;
    int nblkN = (N + TB - 1) / TB;
    int nblkE = (E + TB - 1) / TB;
    int nscan = (N + 4095) / 4096;

    // --- CSR build (same topology for all layers) ---
    hipMemsetAsync(tmp, 0, (size_t)N * 4, stream);
    k_count<<<nblkE, TB, 0, stream>>>(tgt, tmp, E);
    k_scanA<<<nscan, TB, 0, stream>>>(tmp, rowptr, bsums, N);
    k_scanB<<<1, 64, 0, stream>>>(bsums, rowptr, nscan, N);
    k_scanC<<<nblkN, TB, 0, stream>>>(rowptr, bsums, edst, tmp, N);
    k_scatter<<<nblkE, TB, 0, stream>>>(src, tgt, tmp, edst, E);

    int gemmBlocks = (N + 127) / 128;
    int aggBlocks = (N + 15) / 16;

    // --- layer 0: x[N,128] -> Cb[N,128] ---
    k_gemm_fused<128><<<gemmBlocks, TB, 0, stream>>>(x, Wl0, Wr0, A, B, N);
    k_agg<4, 32><<<aggBlocks, TB, 0, stream>>>(A, B, att0, b0, rowptr, edst, Cb, N);

    // --- layer 1: Cb -> Cb ---
    k_gemm_fused<128><<<gemmBlocks, TB, 0, stream>>>(Cb, Wl1, Wr1, A, B, N);
    k_agg<4, 32><<<aggBlocks, TB, 0, stream>>>(A, B, att1, b1, rowptr, edst, Cb, N);

    // --- layer 2: Cb[N,128] -> Cb[N,64] ---
    k_gemm_fused<64><<<gemmBlocks, TB, 0, stream>>>(Cb, Wl2, Wr2, A, B, N);
    k_agg<1, 64><<<aggBlocks, TB, 0, stream>>>(A, B, att2, b2, rowptr, edst, Cb, N);

    // --- global mean pool ---
    k_pool<<<G, TB, 0, stream>>>(Cb, batch, (float*)d_out, N);
}

// Round 7
// 491.417 us; speedup vs baseline: 1.1748x; 1.1661x over previous
//
#include <hip/hip_runtime.h>
#include <hip/hip_fp16.h>
#include <math.h>

#define NEGSLOPE 0.2f

__device__ __forceinline__ float lrelu(float x) { return x > 0.f ? x : NEGSLOPE * x; }

// ---------------- CSR build ----------------
__global__ void k_count(const int* __restrict__ tgt, int* __restrict__ deg, int e) {
    int i = blockIdx.x * 256 + threadIdx.x;
    if (i < e) atomicAdd(&deg[tgt[i]], 1);
}
// block scans 4096 elements (256 threads x 16); +1 per element folds in the self-loop
__global__ __launch_bounds__(256) void k_scanA(const int* __restrict__ deg, int* __restrict__ rowptr,
                                               int* __restrict__ bsums, int n) {
    __shared__ int s[256];
    int t = threadIdx.x;
    int base = blockIdx.x * 4096 + t * 16;
    int pre[16];
    int sum = 0;
    for (int i = 0; i < 16; ++i) {
        int idx = base + i;
        int v = (idx < n) ? (deg[idx] + 1) : 0;
        pre[i] = sum;
        sum += v;
    }
    s[t] = sum;
    __syncthreads();
    for (int off = 1; off < 256; off <<= 1) {
        int v = (t >= off) ? s[t - off] : 0;
        __syncthreads();
        s[t] += v;
        __syncthreads();
    }
    int tbase = s[t] - sum;   // exclusive base for this thread within block
    for (int i = 0; i < 16; ++i) {
        int idx = base + i;
        if (idx < n) rowptr[idx] = tbase + pre[i];
    }
    if (t == 0) bsums[blockIdx.x] = s[255];
}
__global__ void k_scanB(int* __restrict__ bsums, int* __restrict__ rowptr, int nblk, int n) {
    if (threadIdx.x == 0 && blockIdx.x == 0) {
        int run = 0;
        for (int i = 0; i < nblk; ++i) { int v = bsums[i]; bsums[i] = run; run += v; }
        rowptr[n] = run;   // Etot
    }
}
// finalize rowptr, seed self-loop edge, init scatter cursor — one pass
__global__ void k_scanC(int* __restrict__ rowptr, const int* __restrict__ bsums,
                        int* __restrict__ edst, int* __restrict__ cursor, int n) {
    int i = blockIdx.x * 256 + threadIdx.x;
    if (i < n) {
        int rp = rowptr[i] + bsums[i >> 12];   // 4096 per scan block
        rowptr[i] = rp;
        edst[rp] = i;                          // self loop first in each row
        cursor[i] = rp + 1;
    }
}
__global__ void k_scatter(const int* __restrict__ src, const int* __restrict__ tgt,
                          int* __restrict__ cursor, int* __restrict__ edst, int e) {
    int i = blockIdx.x * 256 + threadIdx.x;
    if (i < e) { int p = atomicAdd(&cursor[tgt[i]], 1); edst[p] = src[i]; }
}

// ---------------- fused GEMM: out0 = half(A@W0), out1 = A@W1 ------------------
// 128x128 output tile, 8x8 micro-tile, K chunked at 32, A k-major in LDS.
// KOUT=128: blockIdx.y picks the W0 (->half out0) or W1 (->float out1) pass.
// KOUT=64: single pass, cols [0,64)=W0->out0(half), [64,128)=W1->out1(float).
template<int KOUT>
__global__ __launch_bounds__(256) void k_gemm_fused(const float* __restrict__ Ain,
        const float* __restrict__ W0, const float* __restrict__ W1,
        __half* __restrict__ out0, float* __restrict__ out1, int n) {
    __shared__ float Ast[32][132];           // A chunk, k-major: Ast[k][row]
    __shared__ float Wt[32][132];            // W chunk, row-major: Wt[k][col]
    int t = threadIdx.x;
    int ct = blockIdx.y;
    int w = t >> 6, lane = t & 63;
    int rg = (lane >> 3) + 8 * (w & 1);      // 0..15
    int cg = (lane & 7) + 8 * (w >> 1);      // 0..15
    int r0 = rg * 8, c0 = cg * 8;
    int row0 = blockIdx.x * 128;

    float acc[8][8] = {};
    for (int kc = 0; kc < 4; ++kc) {
        int kb = kc * 32;
        __syncthreads();                     // drain prior reads before overwrite
        // stage A chunk transposed: 128 rows x 32 k
        for (int i = 0; i < 4; ++i) {
            int idx = t + 256 * i;
            int r = idx >> 3, kq = idx & 7;
            float4 v = make_float4(0.f, 0.f, 0.f, 0.f);
            int gr = row0 + r;
            if (gr < n) v = *(const float4*)(Ain + (size_t)gr * 128 + kb + 4 * kq);
            Ast[4 * kq + 0][r] = v.x; Ast[4 * kq + 1][r] = v.y;
            Ast[4 * kq + 2][r] = v.z; Ast[4 * kq + 3][r] = v.w;
        }
        // stage W chunk: 32 k x 128 cols
        for (int i = 0; i < 4; ++i) {
            int idx = t + 256 * i;
            int k = idx >> 5, cq = idx & 31;
            float4 v;
            if (KOUT == 128) {
                const float* W = ct ? W1 : W0;
                v = *(const float4*)(W + (size_t)(kb + k) * 128 + 4 * cq);
            } else {  // cols [0,64)=W0, [64,128)=W1
                const float* W = (cq < 16) ? W0 : W1;
                int c = (cq < 16) ? 4 * cq : 4 * (cq - 16);
                v = *(const float4*)(W + (size_t)(kb + k) * 64 + c);
            }
            *(float4*)&Wt[k][4 * cq] = v;
        }
        __syncthreads();
#pragma unroll 2
        for (int k = 0; k < 32; ++k) {
            float a_[8], b_[8];
            *(float4*)&a_[0] = *(const float4*)&Ast[k][r0];
            *(float4*)&a_[4] = *(const float4*)&Ast[k][r0 + 4];
            *(float4*)&b_[0] = *(const float4*)&Wt[k][c0];
            *(float4*)&b_[4] = *(const float4*)&Wt[k][c0 + 4];
#pragma unroll
            for (int i = 0; i < 8; ++i)
#pragma unroll
                for (int j = 0; j < 8; ++j)
                    acc[i][j] += a_[i] * b_[j];
        }
    }
    // write 8x8 micro-tile
    bool asHalf = (KOUT == 128) ? (ct == 0) : (cg < 8);
    int c = (KOUT == 128) ? c0 : ((cg < 8) ? c0 : c0 - 64);
    for (int i = 0; i < 8; ++i) {
        int gr = row0 + r0 + i;
        if (gr >= n) break;
        if (asHalf) {
            union { uint4 u; __half2 h[4]; } pk;
#pragma unroll
            for (int j = 0; j < 4; ++j)
                pk.h[j] = __float22half2_rn(make_float2(acc[i][2 * j], acc[i][2 * j + 1]));
            *(uint4*)(out0 + (size_t)gr * KOUT + c) = pk.u;
        } else {
            *(float4*)(out1 + (size_t)gr * KOUT + c)     = *(float4*)&acc[i][0];
            *(float4*)(out1 + (size_t)gr * KOUT + c + 4) = *(float4*)&acc[i][4];
        }
    }
}

// ---------------- GATv2 aggregation: 4 nodes per wave, 16 lanes per node ------
// xl (gathered payload) is fp16: VEC=8 lane load = one 16B b128.
// Lane holds VEC = F/16 channels. Head spans L = C/VEC lanes (4 for H=4, 16 for H=1).
// Edge loop unrolled x4: 16 independent row gathers in flight per wave.
// No max-subtraction (scores bounded -> exp(p)/sum exp(p) identical to ref softmax).
template<int H, int C>
__global__ __launch_bounds__(256) void k_agg(const __half* __restrict__ xl, const float* __restrict__ xr,
                                             const float* __restrict__ att, const float* __restrict__ bias,
                                             const int* __restrict__ rowptr, const int* __restrict__ edst,
                                             float* __restrict__ yout, int n) {
    constexpr int F = H * C;
    constexpr int VEC = F / 16;      // 8 (F=128) or 4 (F=64)
    constexpr int L = C / VEC;       // lanes per head: 4 or 16
    int lane = threadIdx.x & 63;
    int wave = threadIdx.x >> 6;
    int s = lane & 15;               // sublane within node group
    int node = blockIdx.x * 16 + wave * 4 + (lane >> 4);
    bool valid = node < n;
    int nodeSafe = valid ? node : 0;
    int ch = s * VEC;

    float u[VEC], av[VEC], acc[VEC];
#pragma unroll
    for (int j = 0; j < VEC; ++j) {
        u[j] = xr[(size_t)nodeSafe * F + ch + j];
        av[j] = att[ch + j];
        acc[j] = 0.f;
    }
    int e0 = rowptr[nodeSafe];
    int deg = valid ? (rowptr[nodeSafe + 1] - e0) : 0;
    int maxdeg = deg;                // wave-uniform max degree over the 4 node groups
    maxdeg = max(maxdeg, __shfl_xor(maxdeg, 16));
    maxdeg = max(maxdeg, __shfl_xor(maxdeg, 32));
    float ssum = 0.f;

    auto loadrow = [&](int src, float* v) {
        const __half* p = xl + (size_t)src * F + ch;
        if constexpr (VEC == 8) {
            union { uint4 u4; __half2 h[4]; } pk;
            pk.u4 = *(const uint4*)p;
#pragma unroll
            for (int j = 0; j < 4; ++j) {
                float2 f = __half22float2(pk.h[j]);
                v[2 * j] = f.x; v[2 * j + 1] = f.y;
            }
        } else {
            union { uint2 u2; __half2 h[2]; } pk;
            pk.u2 = *(const uint2*)p;
#pragma unroll
            for (int j = 0; j < 2; ++j) {
                float2 f = __half22float2(pk.h[j]);
                v[2 * j] = f.x; v[2 * j + 1] = f.y;
            }
        }
    };
    auto dot = [&](const float* v) {
        float p = 0.f;
#pragma unroll
        for (int j = 0; j < VEC; ++j) p += lrelu(v[j] + u[j]) * av[j];
        return p;
    };
    auto accum = [&](float w, const float* v) {
        ssum += w;
#pragma unroll
        for (int j = 0; j < VEC; ++j) acc[j] += w * v[j];
    };

    for (int base = 0; base < maxdeg; base += 16) {
        int cnt = deg - base;                        // group-uniform
        if (cnt > 16) cnt = 16;
        int idxreg = (s < cnt) ? edst[e0 + base + s] : nodeSafe;
        int mcnt = cnt;                              // wave max for this chunk
        mcnt = max(mcnt, __shfl_xor(mcnt, 16));
        mcnt = max(mcnt, __shfl_xor(mcnt, 32));
        int gbase = lane & 48;                       // group<<4
        int i = 0;
        for (; i + 4 <= mcnt; i += 4) {
            int s0 = __shfl(idxreg, gbase + i);
            int s1 = __shfl(idxreg, gbase + i + 1);
            int s2 = __shfl(idxreg, gbase + i + 2);
            int s3 = __shfl(idxreg, gbase + i + 3);
            float v0[VEC], v1[VEC], v2[VEC], v3[VEC];
            loadrow(s0, v0); loadrow(s1, v1); loadrow(s2, v2); loadrow(s3, v3);
            float p0 = dot(v0), p1 = dot(v1), p2 = dot(v2), p3 = dot(v3);
#pragma unroll
            for (int off = 1; off < L; off <<= 1) {
                p0 += __shfl_xor(p0, off);
                p1 += __shfl_xor(p1, off);
                p2 += __shfl_xor(p2, off);
                p3 += __shfl_xor(p3, off);
            }
            float w0 = (i + 0 < cnt) ? __expf(p0) : 0.f;
            float w1 = (i + 1 < cnt) ? __expf(p1) : 0.f;
            float w2 = (i + 2 < cnt) ? __expf(p2) : 0.f;
            float w3 = (i + 3 < cnt) ? __expf(p3) : 0.f;
            accum(w0, v0); accum(w1, v1); accum(w2, v2); accum(w3, v3);
        }
        for (; i < mcnt; ++i) {
            int s0 = __shfl(idxreg, gbase + i);
            float v[VEC];
            loadrow(s0, v);
            float p = dot(v);
#pragma unroll
            for (int off = 1; off < L; off <<= 1) p += __shfl_xor(p, off);
            float w = (i < cnt) ? __expf(p) : 0.f;
            accum(w, v);
        }
    }
    if (valid) {
        float inv = 1.f / ssum;
        float o[VEC];
#pragma unroll
        for (int j = 0; j < VEC; ++j) o[j] = lrelu(acc[j] * inv + bias[ch + j]);
        float* p = yout + (size_t)node * F + ch;
        *(float4*)p = *(float4*)o;
        if constexpr (VEC == 8) *(float4*)(p + 4) = *(float4*)(o + 4);
    }
}

// ---------------- global mean pool (batch sorted -> binary-search ranges) ----------------
__global__ __launch_bounds__(256) void k_pool(const float* __restrict__ y, const int* __restrict__ batch,
                                              float* __restrict__ out, int n) {
    __shared__ float sdata[256];
    __shared__ int range[2];
    int g = blockIdx.x;
    int t = threadIdx.x;
    if (t == 0) {
        int lo = 0, hi = n;
        while (lo < hi) { int mid = (lo + hi) >> 1; if (batch[mid] < g) lo = mid + 1; else hi = mid; }
        range[0] = lo;
        hi = n;
        while (lo < hi) { int mid = (lo + hi) >> 1; if (batch[mid] < g + 1) lo = mid + 1; else hi = mid; }
        range[1] = lo;
    }
    __syncthreads();
    int start = range[0], end = range[1];
    int ch = t & 63, sub = t >> 6;
    float acc = 0.f;
    for (int node = start + sub; node < end; node += 4)
        acc += y[(size_t)node * 64 + ch];
    sdata[t] = acc;
    __syncthreads();
    if (t < 128) sdata[t] += sdata[t + 128];
    __syncthreads();
    if (t < 64) {
        float s = sdata[t] + sdata[t + 64];
        float cnt = (float)(end - start);
        out[g * 64 + t] = s / fmaxf(cnt, 1.f);
    }
}

extern "C" void kernel_launch(void* const* d_in, const int* in_sizes, int n_in,
                              void* d_out, int out_size, void* d_ws, size_t ws_size,
                              hipStream_t stream) {
    const float* x     = (const float*)d_in[0];
    const int*   ei    = (const int*)d_in[1];
    const int*   batch = (const int*)d_in[2];
    const float* Wl0 = (const float*)d_in[3];
    const float* Wr0 = (const float*)d_in[4];
    const float* att0 = (const float*)d_in[5];
    const float* b0  = (const float*)d_in[6];
    const float* Wl1 = (const float*)d_in[7];
    const float* Wr1 = (const float*)d_in[8];
    const float* att1 = (const float*)d_in[9];
    const float* b1  = (const float*)d_in[10];
    const float* Wl2 = (const float*)d_in[11];
    const float* Wr2 = (const float*)d_in[12];
    const float* att2 = (const float*)d_in[13];
    const float* b2  = (const float*)d_in[14];

    const int N = in_sizes[2];        // 50000
    const int E = in_sizes[1] / 2;    // 800000
    const int G = out_size / 64;      // 64
    const int* src = ei;
    const int* tgt = ei + E;

    // workspace layout (all 256B aligned)
    size_t off = 0;
    auto take = [&](size_t bytes) {
        void* p = (char*)d_ws + off;
        off = (off + bytes + 255) & ~(size_t)255;
        return p;
    };
    __half* A   = (__half*)take((size_t)N * 128 * 2); // xl (fp16 gather payload)
    float* B    = (float*)take((size_t)N * 128 * 4);  // xr
    float* Cb   = (float*)take((size_t)N * 128 * 4);  // layer output / next input
    int* rowptr = (int*)take((size_t)(N + 1) * 4);
    int* tmp    = (int*)take((size_t)N * 4);          // deg, then cursor
    int* edst   = (int*)take((size_t)(E + N) * 4);
    int* bsums  = (int*)take(64 * 4);
    (void)ws_size; (void)n_in;

    const int TB = 256;
    int nblkN = (N + TB - 1) / TB;
    int nblkE = (E + TB - 1) / TB;
    int nscan = (N + 4095) / 4096;

    // --- CSR build (same topology for all layers) ---
    hipMemsetAsync(tmp, 0, (size_t)N * 4, stream);
    k_count<<<nblkE, TB, 0, stream>>>(tgt, tmp, E);
    k_scanA<<<nscan, TB, 0, stream>>>(tmp, rowptr, bsums, N);
    k_scanB<<<1, 64, 0, stream>>>(bsums, rowptr, nscan, N);
    k_scanC<<<nblkN, TB, 0, stream>>>(rowptr, bsums, edst, tmp, N);
    k_scatter<<<nblkE, TB, 0, stream>>>(src, tgt, tmp, edst, E);

    int gemmBlocks = (N + 127) / 128;
    dim3 gemmGrid2(gemmBlocks, 2);    // KOUT=128: W0/W1 passes split across y
    dim3 gemmGrid1(gemmBlocks, 1);    // KOUT=64: merged single pass
    int aggBlocks = (N + 15) / 16;

    // --- layer 0: x[N,128] -> Cb[N,128] ---
    k_gemm_fused<128><<<gemmGrid2, TB, 0, stream>>>(x, Wl0, Wr0, A, B, N);
    k_agg<4, 32><<<aggBlocks, TB, 0, stream>>>(A, B, att0, b0, rowptr, edst, Cb, N);

    // --- layer 1: Cb -> Cb ---
    k_gemm_fused<128><<<gemmGrid2, TB, 0, stream>>>(Cb, Wl1, Wr1, A, B, N);
    k_agg<4, 32><<<aggBlocks, TB, 0, stream>>>(A, B, att1, b1, rowptr, edst, Cb, N);

    // --- layer 2: Cb[N,128] -> Cb[N,64] ---
    k_gemm_fused<64><<<gemmGrid1, TB, 0, stream>>>(Cb, Wl2, Wr2, A, B, N);
    k_agg<1, 64><<<aggBlocks, TB, 0, stream>>>(A, B, att2, b2, rowptr, edst, Cb, N);

    // --- global mean pool ---
    k_pool<<<G, TB, 0, stream>>>(Cb, batch, (float*)d_out, N);
}

// Round 8
// 442.445 us; speedup vs baseline: 1.3049x; 1.1107x over previous
//
#include <hip/hip_runtime.h>
#include <hip/hip_fp16.h>
#include <math.h>

#define NEGSLOPE 0.2f

__device__ __forceinline__ float lrelu(float x) { return x > 0.f ? x : NEGSLOPE * x; }

// ---------------- CSR build ----------------
__global__ void k_count(const int* __restrict__ tgt, int* __restrict__ deg, int e) {
    int i = blockIdx.x * 256 + threadIdx.x;
    if (i < e) atomicAdd(&deg[tgt[i]], 1);
}
// block scans 4096 elements (256 threads x 16); +1 per element folds in the self-loop
__global__ __launch_bounds__(256) void k_scanA(const int* __restrict__ deg, int* __restrict__ rowptr,
                                               int* __restrict__ bsums, int n) {
    __shared__ int s[256];
    int t = threadIdx.x;
    int base = blockIdx.x * 4096 + t * 16;
    int pre[16];
    int sum = 0;
    for (int i = 0; i < 16; ++i) {
        int idx = base + i;
        int v = (idx < n) ? (deg[idx] + 1) : 0;
        pre[i] = sum;
        sum += v;
    }
    s[t] = sum;
    __syncthreads();
    for (int off = 1; off < 256; off <<= 1) {
        int v = (t >= off) ? s[t - off] : 0;
        __syncthreads();
        s[t] += v;
        __syncthreads();
    }
    int tbase = s[t] - sum;   // exclusive base for this thread within block
    for (int i = 0; i < 16; ++i) {
        int idx = base + i;
        if (idx < n) rowptr[idx] = tbase + pre[i];
    }
    if (t == 0) bsums[blockIdx.x] = s[255];
}
__global__ void k_scanB(int* __restrict__ bsums, int* __restrict__ rowptr, int nblk, int n) {
    if (threadIdx.x == 0 && blockIdx.x == 0) {
        int run = 0;
        for (int i = 0; i < nblk; ++i) { int v = bsums[i]; bsums[i] = run; run += v; }
        rowptr[n] = run;   // Etot
    }
}
// finalize rowptr, seed self-loop edge, init scatter cursor — one pass
__global__ void k_scanC(int* __restrict__ rowptr, const int* __restrict__ bsums,
                        int* __restrict__ edst, int* __restrict__ cursor, int n) {
    int i = blockIdx.x * 256 + threadIdx.x;
    if (i < n) {
        int rp = rowptr[i] + bsums[i >> 12];   // 4096 per scan block
        rowptr[i] = rp;
        edst[rp] = i;                          // self loop first in each row
        cursor[i] = rp + 1;
    }
}
__global__ void k_scatter(const int* __restrict__ src, const int* __restrict__ tgt,
                          int* __restrict__ cursor, int* __restrict__ edst, int e) {
    int i = blockIdx.x * 256 + threadIdx.x;
    if (i < e) { int p = atomicAdd(&cursor[tgt[i]], 1); edst[p] = src[i]; }
}

// ---------------- fused GEMM: out0 = half(A@W0), out1 = A@W1 ------------------
// 128x128 output tile, 8x8 micro-tile, K chunked at 32, A k-major in LDS.
// KOUT=128: blockIdx.y picks the W0 (->half out0) or W1 (->float out1) pass.
// KOUT=64: single pass, cols [0,64)=W0->out0(half), [64,128)=W1->out1(float).
template<int KOUT>
__global__ __launch_bounds__(256) void k_gemm_fused(const float* __restrict__ Ain,
        const float* __restrict__ W0, const float* __restrict__ W1,
        __half* __restrict__ out0, float* __restrict__ out1, int n) {
    __shared__ float Ast[32][132];           // A chunk, k-major: Ast[k][row]
    __shared__ float Wt[32][132];            // W chunk, row-major: Wt[k][col]
    int t = threadIdx.x;
    int ct = blockIdx.y;
    int w = t >> 6, lane = t & 63;
    int rg = (lane >> 3) + 8 * (w & 1);      // 0..15
    int cg = (lane & 7) + 8 * (w >> 1);      // 0..15
    int r0 = rg * 8, c0 = cg * 8;
    int row0 = blockIdx.x * 128;

    float acc[8][8] = {};
    for (int kc = 0; kc < 4; ++kc) {
        int kb = kc * 32;
        __syncthreads();                     // drain prior reads before overwrite
        // stage A chunk transposed: 128 rows x 32 k
        for (int i = 0; i < 4; ++i) {
            int idx = t + 256 * i;
            int r = idx >> 3, kq = idx & 7;
            float4 v = make_float4(0.f, 0.f, 0.f, 0.f);
            int gr = row0 + r;
            if (gr < n) v = *(const float4*)(Ain + (size_t)gr * 128 + kb + 4 * kq);
            Ast[4 * kq + 0][r] = v.x; Ast[4 * kq + 1][r] = v.y;
            Ast[4 * kq + 2][r] = v.z; Ast[4 * kq + 3][r] = v.w;
        }
        // stage W chunk: 32 k x 128 cols
        for (int i = 0; i < 4; ++i) {
            int idx = t + 256 * i;
            int k = idx >> 5, cq = idx & 31;
            float4 v;
            if (KOUT == 128) {
                const float* W = ct ? W1 : W0;
                v = *(const float4*)(W + (size_t)(kb + k) * 128 + 4 * cq);
            } else {  // cols [0,64)=W0, [64,128)=W1
                const float* W = (cq < 16) ? W0 : W1;
                int c = (cq < 16) ? 4 * cq : 4 * (cq - 16);
                v = *(const float4*)(W + (size_t)(kb + k) * 64 + c);
            }
            *(float4*)&Wt[k][4 * cq] = v;
        }
        __syncthreads();
#pragma unroll 2
        for (int k = 0; k < 32; ++k) {
            float a_[8], b_[8];
            *(float4*)&a_[0] = *(const float4*)&Ast[k][r0];
            *(float4*)&a_[4] = *(const float4*)&Ast[k][r0 + 4];
            *(float4*)&b_[0] = *(const float4*)&Wt[k][c0];
            *(float4*)&b_[4] = *(const float4*)&Wt[k][c0 + 4];
#pragma unroll
            for (int i = 0; i < 8; ++i)
#pragma unroll
                for (int j = 0; j < 8; ++j)
                    acc[i][j] += a_[i] * b_[j];
        }
    }
    // write 8x8 micro-tile
    bool asHalf = (KOUT == 128) ? (ct == 0) : (cg < 8);
    int c = (KOUT == 128) ? c0 : ((cg < 8) ? c0 : c0 - 64);
    for (int i = 0; i < 8; ++i) {
        int gr = row0 + r0 + i;
        if (gr >= n) break;
        if (asHalf) {
            union { uint4 u; __half2 h[4]; } pk;
#pragma unroll
            for (int j = 0; j < 4; ++j)
                pk.h[j] = __float22half2_rn(make_float2(acc[i][2 * j], acc[i][2 * j + 1]));
            *(uint4*)(out0 + (size_t)gr * KOUT + c) = pk.u;
        } else {
            *(float4*)(out1 + (size_t)gr * KOUT + c)     = *(float4*)&acc[i][0];
            *(float4*)(out1 + (size_t)gr * KOUT + c + 4) = *(float4*)&acc[i][4];
        }
    }
}

// ---------------- GATv2 aggregation: 4 nodes per wave, 16 lanes per node ------
// xl (gathered payload) is fp16: VEC=8 lane load = one 16B b128.
// Lane holds VEC = F/16 channels. Head spans L = C/VEC lanes (4 for H=4, 16 for H=1).
// Edge loop unrolled x4: 16 independent row gathers in flight per wave.
// No max-subtraction (scores bounded -> exp(p)/sum exp(p) identical to ref softmax).
template<int H, int C>
__global__ __launch_bounds__(256) void k_agg(const __half* __restrict__ xl, const float* __restrict__ xr,
                                             const float* __restrict__ att, const float* __restrict__ bias,
                                             const int* __restrict__ rowptr, const int* __restrict__ edst,
                                             float* __restrict__ yout, int n) {
    constexpr int F = H * C;
    constexpr int VEC = F / 16;      // 8 (F=128) or 4 (F=64)
    constexpr int L = C / VEC;       // lanes per head: 4 or 16
    int lane = threadIdx.x & 63;
    int wave = threadIdx.x >> 6;
    int s = lane & 15;               // sublane within node group
    int node = blockIdx.x * 16 + wave * 4 + (lane >> 4);
    bool valid = node < n;
    int nodeSafe = valid ? node : 0;
    int ch = s * VEC;

    float u[VEC], av[VEC], acc[VEC];
#pragma unroll
    for (int j = 0; j < VEC; ++j) {
        u[j] = xr[(size_t)nodeSafe * F + ch + j];
        av[j] = att[ch + j];
        acc[j] = 0.f;
    }
    int e0 = rowptr[nodeSafe];
    int deg = valid ? (rowptr[nodeSafe + 1] - e0) : 0;
    int maxdeg = deg;                // wave-uniform max degree over the 4 node groups
    maxdeg = max(maxdeg, __shfl_xor(maxdeg, 16));
    maxdeg = max(maxdeg, __shfl_xor(maxdeg, 32));
    float ssum = 0.f;

    auto loadrow = [&](int src, float* v) {
        const __half* p = xl + (size_t)src * F + ch;
        if constexpr (VEC == 8) {
            union { uint4 u4; __half2 h[4]; } pk;
            pk.u4 = *(const uint4*)p;
#pragma unroll
            for (int j = 0; j < 4; ++j) {
                float2 f = __half22float2(pk.h[j]);
                v[2 * j] = f.x; v[2 * j + 1] = f.y;
            }
        } else {
            union { uint2 u2; __half2 h[2]; } pk;
            pk.u2 = *(const uint2*)p;
#pragma unroll
            for (int j = 0; j < 2; ++j) {
                float2 f = __half22float2(pk.h[j]);
                v[2 * j] = f.x; v[2 * j + 1] = f.y;
            }
        }
    };
    auto dot = [&](const float* v) {
        float p = 0.f;
#pragma unroll
        for (int j = 0; j < VEC; ++j) p += lrelu(v[j] + u[j]) * av[j];
        return p;
    };
    auto accum = [&](float w, const float* v) {
        ssum += w;
#pragma unroll
        for (int j = 0; j < VEC; ++j) acc[j] += w * v[j];
    };

    for (int base = 0; base < maxdeg; base += 16) {
        int cnt = deg - base;                        // group-uniform
        if (cnt > 16) cnt = 16;
        int idxreg = (s < cnt) ? edst[e0 + base + s] : nodeSafe;
        int mcnt = cnt;                              // wave max for this chunk
        mcnt = max(mcnt, __shfl_xor(mcnt, 16));
        mcnt = max(mcnt, __shfl_xor(mcnt, 32));
        int gbase = lane & 48;                       // group<<4
        int i = 0;
        for (; i + 4 <= mcnt; i += 4) {
            int s0 = __shfl(idxreg, gbase + i);
            int s1 = __shfl(idxreg, gbase + i + 1);
            int s2 = __shfl(idxreg, gbase + i + 2);
            int s3 = __shfl(idxreg, gbase + i + 3);
            float v0[VEC], v1[VEC], v2[VEC], v3[VEC];
            loadrow(s0, v0); loadrow(s1, v1); loadrow(s2, v2); loadrow(s3, v3);
            float p0 = dot(v0), p1 = dot(v1), p2 = dot(v2), p3 = dot(v3);
#pragma unroll
            for (int off = 1; off < L; off <<= 1) {
                p0 += __shfl_xor(p0, off);
                p1 += __shfl_xor(p1, off);
                p2 += __shfl_xor(p2, off);
                p3 += __shfl_xor(p3, off);
            }
            float w0 = (i + 0 < cnt) ? __expf(p0) : 0.f;
            float w1 = (i + 1 < cnt) ? __expf(p1) : 0.f;
            float w2 = (i + 2 < cnt) ? __expf(p2) : 0.f;
            float w3 = (i + 3 < cnt) ? __expf(p3) : 0.f;
            accum(w0, v0); accum(w1, v1); accum(w2, v2); accum(w3, v3);
        }
        for (; i < mcnt; ++i) {
            int s0 = __shfl(idxreg, gbase + i);
            float v[VEC];
            loadrow(s0, v);
            float p = dot(v);
#pragma unroll
            for (int off = 1; off < L; off <<= 1) p += __shfl_xor(p, off);
            float w = (i < cnt) ? __expf(p) : 0.f;
            accum(w, v);
        }
    }
    if (valid) {
        float inv = 1.f / ssum;
        float o[VEC];
#pragma unroll
        for (int j = 0; j < VEC; ++j) o[j] = lrelu(acc[j] * inv + bias[ch + j]);
        float* p = yout + (size_t)node * F + ch;
        *(float4*)p = *(float4*)o;
        if constexpr (VEC == 8) *(float4*)(p + 4) = *(float4*)(o + 4);
    }
}

// ---------------- hierarchical global mean pool ----------------
// partial: grid (G, NCHUNK); block-reduce a slice of the graph's node range,
// one atomicAdd per channel into zeroed pacc[G][64].
__global__ __launch_bounds__(256) void k_pool_partial(const float* __restrict__ y,
        const int* __restrict__ batch, float* __restrict__ pacc, int n, int nchunk) {
    __shared__ float sdata[256];
    __shared__ int range[2];
    int g = blockIdx.x;
    int chunk = blockIdx.y;
    int t = threadIdx.x;
    if (t == 0) {
        int lo = 0, hi = n;
        while (lo < hi) { int mid = (lo + hi) >> 1; if (batch[mid] < g) lo = mid + 1; else hi = mid; }
        range[0] = lo;
        hi = n;
        while (lo < hi) { int mid = (lo + hi) >> 1; if (batch[mid] < g + 1) lo = mid + 1; else hi = mid; }
        range[1] = lo;
    }
    __syncthreads();
    int start = range[0], len = range[1] - range[0];
    int lo = start + (int)((long long)len * chunk / nchunk);
    int hi = start + (int)((long long)len * (chunk + 1) / nchunk);
    int ch = t & 63, sub = t >> 6;
    float acc = 0.f;
    for (int node = lo + sub; node < hi; node += 4)
        acc += y[(size_t)node * 64 + ch];
    sdata[t] = acc;
    __syncthreads();
    if (t < 128) sdata[t] += sdata[t + 128];
    __syncthreads();
    if (t < 64) atomicAdd(&pacc[g * 64 + t], sdata[t] + sdata[t + 64]);
}
// final: G blocks x 64 threads — divide by count
__global__ void k_pool_final(const float* __restrict__ pacc, const int* __restrict__ batch,
                             float* __restrict__ out, int n) {
    __shared__ int cntS;
    int g = blockIdx.x, t = threadIdx.x;
    if (t == 0) {
        int lo = 0, hi = n;
        while (lo < hi) { int mid = (lo + hi) >> 1; if (batch[mid] < g) lo = mid + 1; else hi = mid; }
        int s = lo;
        hi = n;
        while (lo < hi) { int mid = (lo + hi) >> 1; if (batch[mid] < g + 1) lo = mid + 1; else hi = mid; }
        cntS = lo - s;
    }
    __syncthreads();
    out[g * 64 + t] = pacc[g * 64 + t] / fmaxf((float)cntS, 1.f);
}

extern "C" void kernel_launch(void* const* d_in, const int* in_sizes, int n_in,
                              void* d_out, int out_size, void* d_ws, size_t ws_size,
                              hipStream_t stream) {
    const float* x     = (const float*)d_in[0];
    const int*   ei    = (const int*)d_in[1];
    const int*   batch = (const int*)d_in[2];
    const float* Wl0 = (const float*)d_in[3];
    const float* Wr0 = (const float*)d_in[4];
    const float* att0 = (const float*)d_in[5];
    const float* b0  = (const float*)d_in[6];
    const float* Wl1 = (const float*)d_in[7];
    const float* Wr1 = (const float*)d_in[8];
    const float* att1 = (const float*)d_in[9];
    const float* b1  = (const float*)d_in[10];
    const float* Wl2 = (const float*)d_in[11];
    const float* Wr2 = (const float*)d_in[12];
    const float* att2 = (const float*)d_in[13];
    const float* b2  = (const float*)d_in[14];

    const int N = in_sizes[2];        // 50000
    const int E = in_sizes[1] / 2;    // 800000
    const int G = out_size / 64;      // 64
    const int* src = ei;
    const int* tgt = ei + E;

    // workspace layout (all 256B aligned)
    size_t off = 0;
    auto take = [&](size_t bytes) {
        void* p = (char*)d_ws + off;
        off = (off + bytes + 255) & ~(size_t)255;
        return p;
    };
    __half* A   = (__half*)take((size_t)N * 128 * 2); // xl (fp16 gather payload)
    float* B    = (float*)take((size_t)N * 128 * 4);  // xr
    float* Cb   = (float*)take((size_t)N * 128 * 4);  // layer output / next input
    int* rowptr = (int*)take((size_t)(N + 1) * 4);
    int* tmp    = (int*)take((size_t)N * 4);          // deg, then cursor (zeroed below)
    float* pacc = (float*)take((size_t)G * 64 * 4);   // pool accumulator (zeroed below)
    int* edst   = (int*)take((size_t)(E + N) * 4);
    int* bsums  = (int*)take(64 * 4);
    (void)ws_size; (void)n_in;

    const int TB = 256;
    int nblkN = (N + TB - 1) / TB;
    int nblkE = (E + TB - 1) / TB;
    int nscan = (N + 4095) / 4096;

    // zero deg + pacc in one shot (they're adjacent in the layout)
    hipMemsetAsync(tmp, 0, (size_t)((char*)(pacc + G * 64) - (char*)tmp), stream);

    // --- CSR build (same topology for all layers) ---
    k_count<<<nblkE, TB, 0, stream>>>(tgt, tmp, E);
    k_scanA<<<nscan, TB, 0, stream>>>(tmp, rowptr, bsums, N);
    k_scanB<<<1, 64, 0, stream>>>(bsums, rowptr, nscan, N);
    k_scanC<<<nblkN, TB, 0, stream>>>(rowptr, bsums, edst, tmp, N);
    k_scatter<<<nblkE, TB, 0, stream>>>(src, tgt, tmp, edst, E);

    int gemmBlocks = (N + 127) / 128;
    dim3 gemmGrid2(gemmBlocks, 2);    // KOUT=128: W0/W1 passes split across y
    dim3 gemmGrid1(gemmBlocks, 1);    // KOUT=64: merged single pass
    int aggBlocks = (N + 15) / 16;

    // --- layer 0: x[N,128] -> Cb[N,128] ---
    k_gemm_fused<128><<<gemmGrid2, TB, 0, stream>>>(x, Wl0, Wr0, A, B, N);
    k_agg<4, 32><<<aggBlocks, TB, 0, stream>>>(A, B, att0, b0, rowptr, edst, Cb, N);

    // --- layer 1: Cb -> Cb ---
    k_gemm_fused<128><<<gemmGrid2, TB, 0, stream>>>(Cb, Wl1, Wr1, A, B, N);
    k_agg<4, 32><<<aggBlocks, TB, 0, stream>>>(A, B, att1, b1, rowptr, edst, Cb, N);

    // --- layer 2: Cb[N,128] -> Cb[N,64] ---
    k_gemm_fused<64><<<gemmGrid1, TB, 0, stream>>>(Cb, Wl2, Wr2, A, B, N);
    k_agg<1, 64><<<aggBlocks, TB, 0, stream>>>(A, B, att2, b2, rowptr, edst, Cb, N);

    // --- hierarchical global mean pool ---
    dim3 poolGrid(G, 16);
    k_pool_partial<<<poolGrid, TB, 0, stream>>>(Cb, batch, pacc, N, 16);
    k_pool_final<<<G, 64, 0, stream>>>(pacc, batch, (float*)d_out, N);
}

// Round 9
// 412.854 us; speedup vs baseline: 1.3984x; 1.0717x over previous
//
#include <hip/hip_runtime.h>
#include <hip/hip_fp16.h>
#include <math.h>

#define NEGSLOPE 0.2f

typedef _Float16 f16x8 __attribute__((ext_vector_type(8)));
typedef float f32x4 __attribute__((ext_vector_type(4)));

__device__ __forceinline__ float lrelu(float x) { return x > 0.f ? x : NEGSLOPE * x; }

// ---------------- CSR build ----------------
__global__ void k_count(const int* __restrict__ tgt, int* __restrict__ deg, int e) {
    int i = blockIdx.x * 256 + threadIdx.x;
    if (i < e) atomicAdd(&deg[tgt[i]], 1);
}
// block scans 4096 elements (256 threads x 16); +1 per element folds in the self-loop
__global__ __launch_bounds__(256) void k_scanA(const int* __restrict__ deg, int* __restrict__ rowptr,
                                               int* __restrict__ bsums, int n) {
    __shared__ int s[256];
    int t = threadIdx.x;
    int base = blockIdx.x * 4096 + t * 16;
    int pre[16];
    int sum = 0;
    for (int i = 0; i < 16; ++i) {
        int idx = base + i;
        int v = (idx < n) ? (deg[idx] + 1) : 0;
        pre[i] = sum;
        sum += v;
    }
    s[t] = sum;
    __syncthreads();
    for (int off = 1; off < 256; off <<= 1) {
        int v = (t >= off) ? s[t - off] : 0;
        __syncthreads();
        s[t] += v;
        __syncthreads();
    }
    int tbase = s[t] - sum;   // exclusive base for this thread within block
    for (int i = 0; i < 16; ++i) {
        int idx = base + i;
        if (idx < n) rowptr[idx] = tbase + pre[i];
    }
    if (t == 0) bsums[blockIdx.x] = s[255];
}
__global__ void k_scanB(int* __restrict__ bsums, int* __restrict__ rowptr, int nblk, int n) {
    if (threadIdx.x == 0 && blockIdx.x == 0) {
        int run = 0;
        for (int i = 0; i < nblk; ++i) { int v = bsums[i]; bsums[i] = run; run += v; }
        rowptr[n] = run;   // Etot
    }
}
// finalize rowptr, seed self-loop edge, init scatter cursor — one pass
__global__ void k_scanC(int* __restrict__ rowptr, const int* __restrict__ bsums,
                        int* __restrict__ edst, int* __restrict__ cursor, int n) {
    int i = blockIdx.x * 256 + threadIdx.x;
    if (i < n) {
        int rp = rowptr[i] + bsums[i >> 12];   // 4096 per scan block
        rowptr[i] = rp;
        edst[rp] = i;                          // self loop first in each row
        cursor[i] = rp + 1;
    }
}
__global__ void k_scatter(const int* __restrict__ src, const int* __restrict__ tgt,
                          int* __restrict__ cursor, int* __restrict__ edst, int e) {
    int i = blockIdx.x * 256 + threadIdx.x;
    if (i < e) { int p = atomicAdd(&cursor[tgt[i]], 1); edst[p] = src[i]; }
}

// ---------------- conversions ----------------
// x fp32 -> fp16, 8 elements/thread
__global__ void k_xconv(const float* __restrict__ x, _Float16* __restrict__ xh, int n8) {
    int i = blockIdx.x * 256 + threadIdx.x;
    if (i < n8) {
        float4 a = ((const float4*)x)[2 * i], b = ((const float4*)x)[2 * i + 1];
        union { uint4 u; _Float16 h[8]; } pk;
        pk.h[0] = (_Float16)a.x; pk.h[1] = (_Float16)a.y;
        pk.h[2] = (_Float16)a.z; pk.h[3] = (_Float16)a.w;
        pk.h[4] = (_Float16)b.x; pk.h[5] = (_Float16)b.y;
        pk.h[6] = (_Float16)b.z; pk.h[7] = (_Float16)b.w;
        ((uint4*)xh)[i] = pk.u;
    }
}
// all 6 weights: W[K=128][KOUT] f32 -> Wt[KOUT][128] f16 (transposed)
__global__ void k_wconv(const float* W0, const float* W1, const float* W2,
                        const float* W3, const float* W4, const float* W5,
                        _Float16* D0, _Float16* D1, _Float16* D2,
                        _Float16* D3, _Float16* D4, _Float16* D5) {
    int b = blockIdx.x, k = threadIdx.x;
    const float* src; _Float16* dst; int col, kout;
    if (b < 128)      { src = W0; dst = D0; col = b;       kout = 128; }
    else if (b < 256) { src = W1; dst = D1; col = b - 128; kout = 128; }
    else if (b < 384) { src = W2; dst = D2; col = b - 256; kout = 128; }
    else if (b < 512) { src = W3; dst = D3; col = b - 384; kout = 128; }
    else if (b < 576) { src = W4; dst = D4; col = b - 512; kout = 64; }
    else              { src = W5; dst = D5; col = b - 576; kout = 64; }
    dst[col * 128 + k] = (_Float16)src[k * kout + col];
}

// ---------------- MFMA fp16 GEMM: out0 = half(A@W0), out1 = fp32(A@W1) -------
// A: [n][128] f16. Wt*: [KOUT][128] f16 (transposed weights). No LDS, no barriers.
// Wave = 16 rows x 128 cols: 4 prefetched A-frags, 8 col-tiles x 4 k-steps of
// v_mfma_f32_16x16x32_f16. Frag layouts (verified m89/m91):
//   A[m=lane&15][k=q*8+j], B[k=q*8+j][n=lane&15], D: row=q*4+reg, col=lane&15.
// KOUT=128: blockIdx.y=0 -> W0 -> out0 (f16); y=1 -> W1 -> out1 (f32).
// KOUT=64:  single pass; ct 0-3 -> W0 -> out0, ct 4-7 -> W1 -> out1.
template<int KOUT>
__global__ __launch_bounds__(256) void k_gemm_mfma(
        const _Float16* __restrict__ Ah,
        const _Float16* __restrict__ Wt0, const _Float16* __restrict__ Wt1,
        _Float16* __restrict__ out0, float* __restrict__ out1, int n) {
    int wv = threadIdx.x >> 6, lane = threadIdx.x & 63;
    int m = lane & 15, q = lane >> 4;
    int row0 = blockIdx.x * 64 + wv * 16;
    int arow = row0 + m; if (arow >= n) arow = n - 1;
    const _Float16* ap = Ah + (size_t)arow * 128 + q * 8;
    f16x8 af[4];
#pragma unroll
    for (int kt = 0; kt < 4; ++kt) af[kt] = *(const f16x8*)(ap + 32 * kt);

    f32x4 acc[8] = {};
    const _Float16* Wsel = Wt0;
    if (KOUT == 128 && blockIdx.y) Wsel = Wt1;
#pragma unroll
    for (int kt = 0; kt < 4; ++kt) {
#pragma unroll
        for (int ct = 0; ct < 8; ++ct) {
            const _Float16* W = (KOUT == 128) ? Wsel : (ct < 4 ? Wt0 : Wt1);
            int col0 = (KOUT == 128) ? ct * 16 : (ct & 3) * 16;
            f16x8 bf = *(const f16x8*)(W + (size_t)(col0 + m) * 128 + 32 * kt + 8 * q);
            acc[ct] = __builtin_amdgcn_mfma_f32_16x16x32_f16(af[kt], bf, acc[ct], 0, 0, 0);
        }
    }
#pragma unroll
    for (int ct = 0; ct < 8; ++ct) {
        bool asHalf = (KOUT == 128) ? (blockIdx.y == 0) : (ct < 4);
        int col0 = (KOUT == 128) ? ct * 16 : (ct & 3) * 16;
        int col = col0 + m;
#pragma unroll
        for (int i = 0; i < 4; ++i) {
            int r = row0 + q * 4 + i;
            if (r < n) {
                if (asHalf) out0[(size_t)r * KOUT + col] = (_Float16)acc[ct][i];
                else        out1[(size_t)r * KOUT + col] = acc[ct][i];
            }
        }
    }
}

// ---------------- GATv2 aggregation: 4 nodes per wave, 16 lanes per node ------
// xl (gathered payload) fp16; output OutT (fp16 for layers feeding a GEMM,
// fp32 for the last layer feeding the pool). No max-subtraction (scores
// bounded -> exp(p)/sum exp(p) identical to ref softmax). Edge loop x4.
template<int H, int C, typename OutT>
__global__ __launch_bounds__(256) void k_agg(const __half* __restrict__ xl, const float* __restrict__ xr,
                                             const float* __restrict__ att, const float* __restrict__ bias,
                                             const int* __restrict__ rowptr, const int* __restrict__ edst,
                                             OutT* __restrict__ yout, int n) {
    constexpr int F = H * C;
    constexpr int VEC = F / 16;      // 8 (F=128) or 4 (F=64)
    constexpr int L = C / VEC;       // lanes per head: 4 or 16
    int lane = threadIdx.x & 63;
    int wave = threadIdx.x >> 6;
    int s = lane & 15;               // sublane within node group
    int node = blockIdx.x * 16 + wave * 4 + (lane >> 4);
    bool valid = node < n;
    int nodeSafe = valid ? node : 0;
    int ch = s * VEC;

    float u[VEC], av[VEC], acc[VEC];
#pragma unroll
    for (int j = 0; j < VEC; ++j) {
        u[j] = xr[(size_t)nodeSafe * F + ch + j];
        av[j] = att[ch + j];
        acc[j] = 0.f;
    }
    int e0 = rowptr[nodeSafe];
    int deg = valid ? (rowptr[nodeSafe + 1] - e0) : 0;
    int maxdeg = deg;                // wave-uniform max degree over the 4 node groups
    maxdeg = max(maxdeg, __shfl_xor(maxdeg, 16));
    maxdeg = max(maxdeg, __shfl_xor(maxdeg, 32));
    float ssum = 0.f;

    auto loadrow = [&](int src, float* v) {
        const __half* p = xl + (size_t)src * F + ch;
        if constexpr (VEC == 8) {
            union { uint4 u4; __half2 h[4]; } pk;
            pk.u4 = *(const uint4*)p;
#pragma unroll
            for (int j = 0; j < 4; ++j) {
                float2 f = __half22float2(pk.h[j]);
                v[2 * j] = f.x; v[2 * j + 1] = f.y;
            }
        } else {
            union { uint2 u2; __half2 h[2]; } pk;
            pk.u2 = *(const uint2*)p;
#pragma unroll
            for (int j = 0; j < 2; ++j) {
                float2 f = __half22float2(pk.h[j]);
                v[2 * j] = f.x; v[2 * j + 1] = f.y;
            }
        }
    };
    auto dot = [&](const float* v) {
        float p = 0.f;
#pragma unroll
        for (int j = 0; j < VEC; ++j) p += lrelu(v[j] + u[j]) * av[j];
        return p;
    };
    auto accum = [&](float w, const float* v) {
        ssum += w;
#pragma unroll
        for (int j = 0; j < VEC; ++j) acc[j] += w * v[j];
    };

    for (int base = 0; base < maxdeg; base += 16) {
        int cnt = deg - base;                        // group-uniform
        if (cnt > 16) cnt = 16;
        int idxreg = (s < cnt) ? edst[e0 + base + s] : nodeSafe;
        int mcnt = cnt;                              // wave max for this chunk
        mcnt = max(mcnt, __shfl_xor(mcnt, 16));
        mcnt = max(mcnt, __shfl_xor(mcnt, 32));
        int gbase = lane & 48;                       // group<<4
        int i = 0;
        for (; i + 4 <= mcnt; i += 4) {
            int s0 = __shfl(idxreg, gbase + i);
            int s1 = __shfl(idxreg, gbase + i + 1);
            int s2 = __shfl(idxreg, gbase + i + 2);
            int s3 = __shfl(idxreg, gbase + i + 3);
            float v0[VEC], v1[VEC], v2[VEC], v3[VEC];
            loadrow(s0, v0); loadrow(s1, v1); loadrow(s2, v2); loadrow(s3, v3);
            float p0 = dot(v0), p1 = dot(v1), p2 = dot(v2), p3 = dot(v3);
#pragma unroll
            for (int off = 1; off < L; off <<= 1) {
                p0 += __shfl_xor(p0, off);
                p1 += __shfl_xor(p1, off);
                p2 += __shfl_xor(p2, off);
                p3 += __shfl_xor(p3, off);
            }
            float w0 = (i + 0 < cnt) ? __expf(p0) : 0.f;
            float w1 = (i + 1 < cnt) ? __expf(p1) : 0.f;
            float w2 = (i + 2 < cnt) ? __expf(p2) : 0.f;
            float w3 = (i + 3 < cnt) ? __expf(p3) : 0.f;
            accum(w0, v0); accum(w1, v1); accum(w2, v2); accum(w3, v3);
        }
        for (; i < mcnt; ++i) {
            int s0 = __shfl(idxreg, gbase + i);
            float v[VEC];
            loadrow(s0, v);
            float p = dot(v);
#pragma unroll
            for (int off = 1; off < L; off <<= 1) p += __shfl_xor(p, off);
            float w = (i < cnt) ? __expf(p) : 0.f;
            accum(w, v);
        }
    }
    if (valid) {
        float inv = 1.f / ssum;
        float o[VEC];
#pragma unroll
        for (int j = 0; j < VEC; ++j) o[j] = lrelu(acc[j] * inv + bias[ch + j]);
        if constexpr (sizeof(OutT) == 2) {
            _Float16* p = (_Float16*)yout + (size_t)node * F + ch;
            if constexpr (VEC == 8) {
                union { uint4 u; _Float16 h[8]; } pk;
#pragma unroll
                for (int j = 0; j < 8; ++j) pk.h[j] = (_Float16)o[j];
                *(uint4*)p = pk.u;
            } else {
                union { uint2 u; _Float16 h[4]; } pk;
#pragma unroll
                for (int j = 0; j < 4; ++j) pk.h[j] = (_Float16)o[j];
                *(uint2*)p = pk.u;
            }
        } else {
            float* p = (float*)yout + (size_t)node * F + ch;
            *(float4*)p = make_float4(o[0], o[1], o[2], o[3]);
            if constexpr (VEC == 8)
                *(float4*)(p + 4) = make_float4(o[4], o[5], o[6], o[7]);
        }
    }
}

// ---------------- hierarchical global mean pool ----------------
__global__ __launch_bounds__(256) void k_pool_partial(const float* __restrict__ y,
        const int* __restrict__ batch, float* __restrict__ pacc, int n, int nchunk) {
    __shared__ float sdata[256];
    __shared__ int range[2];
    int g = blockIdx.x;
    int chunk = blockIdx.y;
    int t = threadIdx.x;
    if (t == 0) {
        int lo = 0, hi = n;
        while (lo < hi) { int mid = (lo + hi) >> 1; if (batch[mid] < g) lo = mid + 1; else hi = mid; }
        range[0] = lo;
        hi = n;
        while (lo < hi) { int mid = (lo + hi) >> 1; if (batch[mid] < g + 1) lo = mid + 1; else hi = mid; }
        range[1] = lo;
    }
    __syncthreads();
    int start = range[0], len = range[1] - range[0];
    int lo = start + (int)((long long)len * chunk / nchunk);
    int hi = start + (int)((long long)len * (chunk + 1) / nchunk);
    int ch = t & 63, sub = t >> 6;
    float acc = 0.f;
    for (int node = lo + sub; node < hi; node += 4)
        acc += y[(size_t)node * 64 + ch];
    sdata[t] = acc;
    __syncthreads();
    if (t < 128) sdata[t] += sdata[t + 128];
    __syncthreads();
    if (t < 64) atomicAdd(&pacc[g * 64 + t], sdata[t] + sdata[t + 64]);
}
__global__ void k_pool_final(const float* __restrict__ pacc, const int* __restrict__ batch,
                             float* __restrict__ out, int n) {
    __shared__ int cntS;
    int g = blockIdx.x, t = threadIdx.x;
    if (t == 0) {
        int lo = 0, hi = n;
        while (lo < hi) { int mid = (lo + hi) >> 1; if (batch[mid] < g) lo = mid + 1; else hi = mid; }
        int s = lo;
        hi = n;
        while (lo < hi) { int mid = (lo + hi) >> 1; if (batch[mid] < g + 1) lo = mid + 1; else hi = mid; }
        cntS = lo - s;
    }
    __syncthreads();
    out[g * 64 + t] = pacc[g * 64 + t] / fmaxf((float)cntS, 1.f);
}

extern "C" void kernel_launch(void* const* d_in, const int* in_sizes, int n_in,
                              void* d_out, int out_size, void* d_ws, size_t ws_size,
                              hipStream_t stream) {
    const float* x     = (const float*)d_in[0];
    const int*   ei    = (const int*)d_in[1];
    const int*   batch = (const int*)d_in[2];
    const float* Wl0 = (const float*)d_in[3];
    const float* Wr0 = (const float*)d_in[4];
    const float* att0 = (const float*)d_in[5];
    const float* b0  = (const float*)d_in[6];
    const float* Wl1 = (const float*)d_in[7];
    const float* Wr1 = (const float*)d_in[8];
    const float* att1 = (const float*)d_in[9];
    const float* b1  = (const float*)d_in[10];
    const float* Wl2 = (const float*)d_in[11];
    const float* Wr2 = (const float*)d_in[12];
    const float* att2 = (const float*)d_in[13];
    const float* b2  = (const float*)d_in[14];

    const int N = in_sizes[2];        // 50000
    const int E = in_sizes[1] / 2;    // 800000
    const int G = out_size / 64;      // 64
    const int* src = ei;
    const int* tgt = ei + E;

    // workspace layout (all 256B aligned)
    size_t off = 0;
    auto take = [&](size_t bytes) {
        void* p = (char*)d_ws + off;
        off = (off + bytes + 255) & ~(size_t)255;
        return p;
    };
    _Float16* xh   = (_Float16*)take((size_t)N * 128 * 2); // x in fp16
    _Float16* Ah   = (_Float16*)take((size_t)N * 128 * 2); // xl (f16, gather payload)
    float* B       = (float*)take((size_t)N * 128 * 4);    // xr (f32)
    _Float16* Cbh  = (_Float16*)take((size_t)N * 128 * 2); // agg out layers 0/1 (f16)
    float* Cbf     = (float*)take((size_t)N * 64 * 4);     // agg out layer 2 (f32)
    _Float16* Wl0t = (_Float16*)take(128 * 128 * 2);
    _Float16* Wr0t = (_Float16*)take(128 * 128 * 2);
    _Float16* Wl1t = (_Float16*)take(128 * 128 * 2);
    _Float16* Wr1t = (_Float16*)take(128 * 128 * 2);
    _Float16* Wl2t = (_Float16*)take(64 * 128 * 2);
    _Float16* Wr2t = (_Float16*)take(64 * 128 * 2);
    int* rowptr = (int*)take((size_t)(N + 1) * 4);
    int* tmp    = (int*)take((size_t)N * 4);          // deg, then cursor (zeroed below)
    float* pacc = (float*)take((size_t)G * 64 * 4);   // pool accumulator (zeroed below)
    int* edst   = (int*)take((size_t)(E + N) * 4);
    int* bsums  = (int*)take(64 * 4);
    (void)ws_size; (void)n_in;

    const int TB = 256;
    int nblkN = (N + TB - 1) / TB;
    int nblkE = (E + TB - 1) / TB;
    int nscan = (N + 4095) / 4096;

    // zero deg + pacc in one shot (adjacent in the layout)
    hipMemsetAsync(tmp, 0, (size_t)((char*)(pacc + G * 64) - (char*)tmp), stream);

    // --- CSR build (same topology for all layers) ---
    k_count<<<nblkE, TB, 0, stream>>>(tgt, tmp, E);
    k_scanA<<<nscan, TB, 0, stream>>>(tmp, rowptr, bsums, N);
    k_scanB<<<1, 64, 0, stream>>>(bsums, rowptr, nscan, N);
    k_scanC<<<nblkN, TB, 0, stream>>>(rowptr, bsums, edst, tmp, N);
    k_scatter<<<nblkE, TB, 0, stream>>>(src, tgt, tmp, edst, E);

    // --- fp16 conversions ---
    k_xconv<<<(N * 128 / 8 + TB - 1) / TB, TB, 0, stream>>>(x, xh, N * 128 / 8);
    k_wconv<<<640, 128, 0, stream>>>(Wl0, Wr0, Wl1, Wr1, Wl2, Wr2,
                                     Wl0t, Wr0t, Wl1t, Wr1t, Wl2t, Wr2t);

    int gemmBlocks = (N + 63) / 64;
    dim3 gemmGrid2(gemmBlocks, 2);    // KOUT=128: W0/W1 passes split across y
    dim3 gemmGrid1(gemmBlocks, 1);    // KOUT=64: merged single pass
    int aggBlocks = (N + 15) / 16;

    // --- layer 0 ---
    k_gemm_mfma<128><<<gemmGrid2, TB, 0, stream>>>(xh, Wl0t, Wr0t, Ah, B, N);
    k_agg<4, 32, _Float16><<<aggBlocks, TB, 0, stream>>>((const __half*)Ah, B, att0, b0, rowptr, edst, Cbh, N);

    // --- layer 1 ---
    k_gemm_mfma<128><<<gemmGrid2, TB, 0, stream>>>(Cbh, Wl1t, Wr1t, Ah, B, N);
    k_agg<4, 32, _Float16><<<aggBlocks, TB, 0, stream>>>((const __half*)Ah, B, att1, b1, rowptr, edst, Cbh, N);

    // --- layer 2 ---
    k_gemm_mfma<64><<<gemmGrid1, TB, 0, stream>>>(Cbh, Wl2t, Wr2t, Ah, B, N);
    k_agg<1, 64, float><<<aggBlocks, TB, 0, stream>>>((const __half*)Ah, B, att2, b2, rowptr, edst, Cbf, N);

    // --- hierarchical global mean pool ---
    dim3 poolGrid(G, 16);
    k_pool_partial<<<poolGrid, TB, 0, stream>>>(Cbf, batch, pacc, N, 16);
    k_pool_final<<<G, 64, 0, stream>>>(pacc, batch, (float*)d_out, N);
}

// Round 10
// 404.082 us; speedup vs baseline: 1.4288x; 1.0217x over previous
//
#include <hip/hip_runtime.h>
#include <hip/hip_fp16.h>
#include <math.h>

#define NEGSLOPE 0.2f

typedef _Float16 f16x8 __attribute__((ext_vector_type(8)));
typedef float f32x4 __attribute__((ext_vector_type(4)));

__device__ __forceinline__ float lrelu(float x) { return x > 0.f ? x : NEGSLOPE * x; }

// ---------------- prep: zero deg/pacc + x->fp16 + weight transpose->fp16 -----
// role-split grid: [0,XB) xconv, [XB,XB+320) weights, rest zeroing.
__global__ __launch_bounds__(256) void k_prep(
        const float* __restrict__ x, _Float16* __restrict__ xh, int n8, int XB,
        const float* W0, const float* W1, const float* W2,
        const float* W3, const float* W4, const float* W5,
        _Float16* D0, _Float16* D1, _Float16* D2,
        _Float16* D3, _Float16* D4, _Float16* D5,
        int* __restrict__ deg, float* __restrict__ pacc, int n, int npacc) {
    int b = blockIdx.x, t = threadIdx.x;
    if (b < XB) {
        int i = b * 256 + t;
        if (i < n8) {
            float4 a = ((const float4*)x)[2 * i], c = ((const float4*)x)[2 * i + 1];
            union { uint4 u; _Float16 h[8]; } pk;
            pk.h[0] = (_Float16)a.x; pk.h[1] = (_Float16)a.y;
            pk.h[2] = (_Float16)a.z; pk.h[3] = (_Float16)a.w;
            pk.h[4] = (_Float16)c.x; pk.h[5] = (_Float16)c.y;
            pk.h[6] = (_Float16)c.z; pk.h[7] = (_Float16)c.w;
            ((uint4*)xh)[i] = pk.u;
        }
    } else if (b < XB + 320) {
        const float* Ws[6] = {W0, W1, W2, W3, W4, W5};
        _Float16* Ds[6] = {D0, D1, D2, D3, D4, D5};
        int j = (b - XB) * 256 + t;
        int m, jj, kout;
        if (j < 65536) { m = j >> 14; jj = j & 16383; kout = 128; }
        else           { m = 4 + ((j - 65536) >> 13); jj = (j - 65536) & 8191; kout = 64; }
        int col = jj >> 7, k = jj & 127;
        Ds[m][col * 128 + k] = (_Float16)Ws[m][k * kout + col];
    } else {
        int i = (b - XB - 320) * 256 + t;
        if (i < n) deg[i] = 0;
        else if (i < n + npacc) pacc[i - n] = 0.f;
    }
}

// ---------------- CSR build ----------------
// count: atomic return value = edge's rank within its target row
__global__ void k_count(const int* __restrict__ tgt, int* __restrict__ deg,
                        int* __restrict__ rank, int e) {
    int i = blockIdx.x * 256 + threadIdx.x;
    if (i < e) rank[i] = atomicAdd(&deg[tgt[i]], 1);
}
// block scans 4096 elements (256 threads x 16); +1 per element folds in the self-loop
__global__ __launch_bounds__(256) void k_scanA(const int* __restrict__ deg, int* __restrict__ rowptr,
                                               int* __restrict__ bsums, int n) {
    __shared__ int s[256];
    int t = threadIdx.x;
    int base = blockIdx.x * 4096 + t * 16;
    int pre[16];
    int sum = 0;
    for (int i = 0; i < 16; ++i) {
        int idx = base + i;
        int v = (idx < n) ? (deg[idx] + 1) : 0;
        pre[i] = sum;
        sum += v;
    }
    s[t] = sum;
    __syncthreads();
    for (int off = 1; off < 256; off <<= 1) {
        int v = (t >= off) ? s[t - off] : 0;
        __syncthreads();
        s[t] += v;
        __syncthreads();
    }
    int tbase = s[t] - sum;   // exclusive base for this thread within block
    for (int i = 0; i < 16; ++i) {
        int idx = base + i;
        if (idx < n) rowptr[idx] = tbase + pre[i];
    }
    if (t == 0) bsums[blockIdx.x] = s[255];
}
// fused scanB+scanC: per-block prefix of bsums (<=64 entries), finalize rowptr,
// seed self-loop edge at row start, write rowptr[n]
__global__ __launch_bounds__(256) void k_scanC(int* __restrict__ rowptr, const int* __restrict__ bsums,
                                               int* __restrict__ edst, int nscan, int n) {
    __shared__ int pref[65];
    int t = threadIdx.x;
    if (t == 0) {
        int run = 0;
        for (int k = 0; k < nscan; ++k) { pref[k] = run; run += bsums[k]; }
        pref[nscan] = run;
    }
    __syncthreads();
    int i = blockIdx.x * 256 + t;
    if (i < n) {
        int rp = rowptr[i] + pref[i >> 12];   // 4096 per scan block
        rowptr[i] = rp;
        edst[rp] = i;                          // self loop first in each row
    }
    if (blockIdx.x == gridDim.x - 1 && t == 0) rowptr[n] = pref[nscan];
}
// scatter: no atomics; slot = rowptr[tgt] + 1 + rank. nt store avoids L2
// dirty-line ping-pong across the 8 non-coherent XCD L2s.
__global__ void k_scatter(const int* __restrict__ src, const int* __restrict__ tgt,
                          const int* __restrict__ rank, const int* __restrict__ rowptr,
                          int* __restrict__ edst, int e) {
    int i = blockIdx.x * 256 + threadIdx.x;
    if (i < e) {
        int p = rowptr[tgt[i]] + 1 + rank[i];
        __builtin_nontemporal_store(src[i], &edst[p]);
    }
}

// ---------------- MFMA fp16 GEMM: out0 = half(A@W0), out1 = fp32(A@W1) -------
// A: [n][128] f16. Wt*: [KOUT][128] f16 (transposed weights). No LDS, no barriers.
// Wave = 16 rows x 2*KOUT cols, both W passes merged (A-frags loaded once).
// Frag layouts (verified m89/m91): A[m=lane&15][k=q*8+j], B[k=q*8+j][n=lane&15],
// D: row=q*4+reg, col=lane&15.
template<int KOUT>
__global__ __launch_bounds__(256) void k_gemm_mfma(
        const _Float16* __restrict__ Ah,
        const _Float16* __restrict__ Wt0, const _Float16* __restrict__ Wt1,
        _Float16* __restrict__ out0, float* __restrict__ out1, int n) {
    constexpr int CT = KOUT / 16;            // col-tiles per weight matrix
    int wv = threadIdx.x >> 6, lane = threadIdx.x & 63;
    int m = lane & 15, q = lane >> 4;
    int row0 = blockIdx.x * 64 + wv * 16;
    int arow = row0 + m; if (arow >= n) arow = n - 1;
    const _Float16* ap = Ah + (size_t)arow * 128 + q * 8;
    f16x8 af[4];
#pragma unroll
    for (int kt = 0; kt < 4; ++kt) af[kt] = *(const f16x8*)(ap + 32 * kt);

    f32x4 acc[2 * CT] = {};
#pragma unroll
    for (int kt = 0; kt < 4; ++kt) {
#pragma unroll
        for (int ct = 0; ct < 2 * CT; ++ct) {
            const _Float16* W = (ct < CT) ? Wt0 : Wt1;
            int col0 = (ct % CT) * 16;
            f16x8 bf = *(const f16x8*)(W + (size_t)(col0 + m) * 128 + 32 * kt + 8 * q);
            acc[ct] = __builtin_amdgcn_mfma_f32_16x16x32_f16(af[kt], bf, acc[ct], 0, 0, 0);
        }
    }
#pragma unroll
    for (int ct = 0; ct < 2 * CT; ++ct) {
        bool asHalf = (ct < CT);
        int col = (ct % CT) * 16 + m;
#pragma unroll
        for (int i = 0; i < 4; ++i) {
            int r = row0 + q * 4 + i;
            if (r < n) {
                if (asHalf) out0[(size_t)r * KOUT + col] = (_Float16)acc[ct][i];
                else        out1[(size_t)r * KOUT + col] = acc[ct][i];
            }
        }
    }
}

// ---------------- GATv2 aggregation: 4 nodes per wave, 16 lanes per node ------
// xl (gathered payload) fp16; output OutT (fp16 for layers feeding a GEMM,
// fp32 for the last layer feeding the pool). No max-subtraction (scores
// bounded -> exp(p)/sum exp(p) identical to ref softmax). Edge loop x4.
template<int H, int C, typename OutT>
__global__ __launch_bounds__(256) void k_agg(const __half* __restrict__ xl, const float* __restrict__ xr,
                                             const float* __restrict__ att, const float* __restrict__ bias,
                                             const int* __restrict__ rowptr, const int* __restrict__ edst,
                                             OutT* __restrict__ yout, int n) {
    constexpr int F = H * C;
    constexpr int VEC = F / 16;      // 8 (F=128) or 4 (F=64)
    constexpr int L = C / VEC;       // lanes per head: 4 or 16
    int lane = threadIdx.x & 63;
    int wave = threadIdx.x >> 6;
    int s = lane & 15;               // sublane within node group
    int node = blockIdx.x * 16 + wave * 4 + (lane >> 4);
    bool valid = node < n;
    int nodeSafe = valid ? node : 0;
    int ch = s * VEC;

    float u[VEC], av[VEC], acc[VEC];
#pragma unroll
    for (int j = 0; j < VEC; ++j) {
        u[j] = xr[(size_t)nodeSafe * F + ch + j];
        av[j] = att[ch + j];
        acc[j] = 0.f;
    }
    int e0 = rowptr[nodeSafe];
    int deg = valid ? (rowptr[nodeSafe + 1] - e0) : 0;
    int maxdeg = deg;                // wave-uniform max degree over the 4 node groups
    maxdeg = max(maxdeg, __shfl_xor(maxdeg, 16));
    maxdeg = max(maxdeg, __shfl_xor(maxdeg, 32));
    float ssum = 0.f;

    auto loadrow = [&](int src, float* v) {
        const __half* p = xl + (size_t)src * F + ch;
        if constexpr (VEC == 8) {
            union { uint4 u4; __half2 h[4]; } pk;
            pk.u4 = *(const uint4*)p;
#pragma unroll
            for (int j = 0; j < 4; ++j) {
                float2 f = __half22float2(pk.h[j]);
                v[2 * j] = f.x; v[2 * j + 1] = f.y;
            }
        } else {
            union { uint2 u2; __half2 h[2]; } pk;
            pk.u2 = *(const uint2*)p;
#pragma unroll
            for (int j = 0; j < 2; ++j) {
                float2 f = __half22float2(pk.h[j]);
                v[2 * j] = f.x; v[2 * j + 1] = f.y;
            }
        }
    };
    auto dot = [&](const float* v) {
        float p = 0.f;
#pragma unroll
        for (int j = 0; j < VEC; ++j) p += lrelu(v[j] + u[j]) * av[j];
        return p;
    };
    auto accum = [&](float w, const float* v) {
        ssum += w;
#pragma unroll
        for (int j = 0; j < VEC; ++j) acc[j] += w * v[j];
    };

    for (int base = 0; base < maxdeg; base += 16) {
        int cnt = deg - base;                        // group-uniform
        if (cnt > 16) cnt = 16;
        int idxreg = (s < cnt) ? edst[e0 + base + s] : nodeSafe;
        int mcnt = cnt;                              // wave max for this chunk
        mcnt = max(mcnt, __shfl_xor(mcnt, 16));
        mcnt = max(mcnt, __shfl_xor(mcnt, 32));
        int gbase = lane & 48;                       // group<<4
        int i = 0;
        for (; i + 4 <= mcnt; i += 4) {
            int s0 = __shfl(idxreg, gbase + i);
            int s1 = __shfl(idxreg, gbase + i + 1);
            int s2 = __shfl(idxreg, gbase + i + 2);
            int s3 = __shfl(idxreg, gbase + i + 3);
            float v0[VEC], v1[VEC], v2[VEC], v3[VEC];
            loadrow(s0, v0); loadrow(s1, v1); loadrow(s2, v2); loadrow(s3, v3);
            float p0 = dot(v0), p1 = dot(v1), p2 = dot(v2), p3 = dot(v3);
#pragma unroll
            for (int off = 1; off < L; off <<= 1) {
                p0 += __shfl_xor(p0, off);
                p1 += __shfl_xor(p1, off);
                p2 += __shfl_xor(p2, off);
                p3 += __shfl_xor(p3, off);
            }
            float w0 = (i + 0 < cnt) ? __expf(p0) : 0.f;
            float w1 = (i + 1 < cnt) ? __expf(p1) : 0.f;
            float w2 = (i + 2 < cnt) ? __expf(p2) : 0.f;
            float w3 = (i + 3 < cnt) ? __expf(p3) : 0.f;
            accum(w0, v0); accum(w1, v1); accum(w2, v2); accum(w3, v3);
        }
        for (; i < mcnt; ++i) {
            int s0 = __shfl(idxreg, gbase + i);
            float v[VEC];
            loadrow(s0, v);
            float p = dot(v);
#pragma unroll
            for (int off = 1; off < L; off <<= 1) p += __shfl_xor(p, off);
            float w = (i < cnt) ? __expf(p) : 0.f;
            accum(w, v);
        }
    }
    if (valid) {
        float inv = 1.f / ssum;
        float o[VEC];
#pragma unroll
        for (int j = 0; j < VEC; ++j) o[j] = lrelu(acc[j] * inv + bias[ch + j]);
        if constexpr (sizeof(OutT) == 2) {
            _Float16* p = (_Float16*)yout + (size_t)node * F + ch;
            if constexpr (VEC == 8) {
                union { uint4 u; _Float16 h[8]; } pk;
#pragma unroll
                for (int j = 0; j < 8; ++j) pk.h[j] = (_Float16)o[j];
                *(uint4*)p = pk.u;
            } else {
                union { uint2 u; _Float16 h[4]; } pk;
#pragma unroll
                for (int j = 0; j < 4; ++j) pk.h[j] = (_Float16)o[j];
                *(uint2*)p = pk.u;
            }
        } else {
            float* p = (float*)yout + (size_t)node * F + ch;
            *(float4*)p = make_float4(o[0], o[1], o[2], o[3]);
            if constexpr (VEC == 8)
                *(float4*)(p + 4) = make_float4(o[4], o[5], o[6], o[7]);
        }
    }
}

// ---------------- hierarchical global mean pool ----------------
__global__ __launch_bounds__(256) void k_pool_partial(const float* __restrict__ y,
        const int* __restrict__ batch, float* __restrict__ pacc, int n, int nchunk) {
    __shared__ float sdata[256];
    __shared__ int range[2];
    int g = blockIdx.x;
    int chunk = blockIdx.y;
    int t = threadIdx.x;
    if (t == 0) {
        int lo = 0, hi = n;
        while (lo < hi) { int mid = (lo + hi) >> 1; if (batch[mid] < g) lo = mid + 1; else hi = mid; }
        range[0] = lo;
        hi = n;
        while (lo < hi) { int mid = (lo + hi) >> 1; if (batch[mid] < g + 1) lo = mid + 1; else hi = mid; }
        range[1] = lo;
    }
    __syncthreads();
    int start = range[0], len = range[1] - range[0];
    int lo = start + (int)((long long)len * chunk / nchunk);
    int hi = start + (int)((long long)len * (chunk + 1) / nchunk);
    int ch = t & 63, sub = t >> 6;
    float acc = 0.f;
    for (int node = lo + sub; node < hi; node += 4)
        acc += y[(size_t)node * 64 + ch];
    sdata[t] = acc;
    __syncthreads();
    if (t < 128) sdata[t] += sdata[t + 128];
    __syncthreads();
    if (t < 64) atomicAdd(&pacc[g * 64 + t], sdata[t] + sdata[t + 64]);
}
__global__ void k_pool_final(const float* __restrict__ pacc, const int* __restrict__ batch,
                             float* __restrict__ out, int n) {
    __shared__ int cntS;
    int g = blockIdx.x, t = threadIdx.x;
    if (t == 0) {
        int lo = 0, hi = n;
        while (lo < hi) { int mid = (lo + hi) >> 1; if (batch[mid] < g) lo = mid + 1; else hi = mid; }
        int s = lo;
        hi = n;
        while (lo < hi) { int mid = (lo + hi) >> 1; if (batch[mid] < g + 1) lo = mid + 1; else hi = mid; }
        cntS = lo - s;
    }
    __syncthreads();
    out[g * 64 + t] = pacc[g * 64 + t] / fmaxf((float)cntS, 1.f);
}

extern "C" void kernel_launch(void* const* d_in, const int* in_sizes, int n_in,
                              void* d_out, int out_size, void* d_ws, size_t ws_size,
                              hipStream_t stream) {
    const float* x     = (const float*)d_in[0];
    const int*   ei    = (const int*)d_in[1];
    const int*   batch = (const int*)d_in[2];
    const float* Wl0 = (const float*)d_in[3];
    const float* Wr0 = (const float*)d_in[4];
    const float* att0 = (const float*)d_in[5];
    const float* b0  = (const float*)d_in[6];
    const float* Wl1 = (const float*)d_in[7];
    const float* Wr1 = (const float*)d_in[8];
    const float* att1 = (const float*)d_in[9];
    const float* b1  = (const float*)d_in[10];
    const float* Wl2 = (const float*)d_in[11];
    const float* Wr2 = (const float*)d_in[12];
    const float* att2 = (const float*)d_in[13];
    const float* b2  = (const float*)d_in[14];

    const int N = in_sizes[2];        // 50000
    const int E = in_sizes[1] / 2;    // 800000
    const int G = out_size / 64;      // 64
    const int* src = ei;
    const int* tgt = ei + E;

    // workspace layout (all 256B aligned)
    size_t off = 0;
    auto take = [&](size_t bytes) {
        void* p = (char*)d_ws + off;
        off = (off + bytes + 255) & ~(size_t)255;
        return p;
    };
    _Float16* xh   = (_Float16*)take((size_t)N * 128 * 2); // x in fp16
    _Float16* Ah   = (_Float16*)take((size_t)N * 128 * 2); // xl (f16, gather payload)
    float* B       = (float*)take((size_t)N * 128 * 4);    // xr (f32)
    _Float16* Cbh  = (_Float16*)take((size_t)N * 128 * 2); // agg out layers 0/1 (f16)
    float* Cbf     = (float*)take((size_t)N * 64 * 4);     // agg out layer 2 (f32)
    _Float16* Wl0t = (_Float16*)take(128 * 128 * 2);
    _Float16* Wr0t = (_Float16*)take(128 * 128 * 2);
    _Float16* Wl1t = (_Float16*)take(128 * 128 * 2);
    _Float16* Wr1t = (_Float16*)take(128 * 128 * 2);
    _Float16* Wl2t = (_Float16*)take(64 * 128 * 2);
    _Float16* Wr2t = (_Float16*)take(64 * 128 * 2);
    int* rowptr = (int*)take((size_t)(N + 1) * 4);
    int* tmp    = (int*)take((size_t)N * 4);          // deg (zeroed in k_prep)
    float* pacc = (float*)take((size_t)G * 64 * 4);   // pool acc (zeroed in k_prep)
    int* rank   = (int*)take((size_t)E * 4);          // edge rank within target row
    int* edst   = (int*)take((size_t)(E + N) * 4);
    int* bsums  = (int*)take(64 * 4);
    (void)ws_size; (void)n_in;

    const int TB = 256;
    int nblkN = (N + TB - 1) / TB;
    int nblkE = (E + TB - 1) / TB;
    int nscan = (N + 4095) / 4096;

    // --- prep: zeroing + fp16 conversions (one launch) ---
    int n8 = N * 128 / 8;
    int XB = (n8 + TB - 1) / TB;
    int ZB = (N + G * 64 + TB - 1) / TB;
    k_prep<<<XB + 320 + ZB, TB, 0, stream>>>(x, xh, n8, XB,
        Wl0, Wr0, Wl1, Wr1, Wl2, Wr2,
        Wl0t, Wr0t, Wl1t, Wr1t, Wl2t, Wr2t,
        tmp, pacc, N, G * 64);

    // --- CSR build: count(+rank), scan, seed self-loops, atomic-free scatter ---
    k_count<<<nblkE, TB, 0, stream>>>(tgt, tmp, rank, E);
    k_scanA<<<nscan, TB, 0, stream>>>(tmp, rowptr, bsums, N);
    k_scanC<<<nblkN, TB, 0, stream>>>(rowptr, bsums, edst, nscan, N);
    k_scatter<<<nblkE, TB, 0, stream>>>(src, tgt, rank, rowptr, edst, E);

    int gemmBlocks = (N + 63) / 64;
    int aggBlocks = (N + 15) / 16;

    // --- layer 0 ---
    k_gemm_mfma<128><<<gemmBlocks, TB, 0, stream>>>(xh, Wl0t, Wr0t, Ah, B, N);
    k_agg<4, 32, _Float16><<<aggBlocks, TB, 0, stream>>>((const __half*)Ah, B, att0, b0, rowptr, edst, Cbh, N);

    // --- layer 1 ---
    k_gemm_mfma<128><<<gemmBlocks, TB, 0, stream>>>(Cbh, Wl1t, Wr1t, Ah, B, N);
    k_agg<4, 32, _Float16><<<aggBlocks, TB, 0, stream>>>((const __half*)Ah, B, att1, b1, rowptr, edst, Cbh, N);

    // --- layer 2 ---
    k_gemm_mfma<64><<<gemmBlocks, TB, 0, stream>>>(Cbh, Wl2t, Wr2t, Ah, B, N);
    k_agg<1, 64, float><<<aggBlocks, TB, 0, stream>>>((const __half*)Ah, B, att2, b2, rowptr, edst, Cbf, N);

    // --- hierarchical global mean pool ---
    dim3 poolGrid(G, 16);
    k_pool_partial<<<poolGrid, TB, 0, stream>>>(Cbf, batch, pacc, N, 16);
    k_pool_final<<<G, 64, 0, stream>>>(pacc, batch, (float*)d_out, N);
}

// Round 11
// 380.621 us; speedup vs baseline: 1.5168x; 1.0616x over previous
//
#include <hip/hip_runtime.h>
#include <hip/hip_fp16.h>
#include <math.h>

#define NEGSLOPE 0.2f

typedef _Float16 f16x8 __attribute__((ext_vector_type(8)));
typedef float f32x4 __attribute__((ext_vector_type(4)));

__device__ __forceinline__ float lrelu(float x) { return x > 0.f ? x : NEGSLOPE * x; }

// ---------------- prep: zero deg/pacc + x->fp16 + weight transpose->fp16 -----
// role-split grid: [0,XB) xconv, [XB,XB+320) weights, rest zeroing.
__global__ __launch_bounds__(256) void k_prep(
        const float* __restrict__ x, _Float16* __restrict__ xh, int n8, int XB,
        const float* W0, const float* W1, const float* W2,
        const float* W3, const float* W4, const float* W5,
        _Float16* D0, _Float16* D1, _Float16* D2,
        _Float16* D3, _Float16* D4, _Float16* D5,
        int* __restrict__ deg, float* __restrict__ pacc, int n, int npacc) {
    int b = blockIdx.x, t = threadIdx.x;
    if (b < XB) {
        int i = b * 256 + t;
        if (i < n8) {
            float4 a = ((const float4*)x)[2 * i], c = ((const float4*)x)[2 * i + 1];
            union { uint4 u; _Float16 h[8]; } pk;
            pk.h[0] = (_Float16)a.x; pk.h[1] = (_Float16)a.y;
            pk.h[2] = (_Float16)a.z; pk.h[3] = (_Float16)a.w;
            pk.h[4] = (_Float16)c.x; pk.h[5] = (_Float16)c.y;
            pk.h[6] = (_Float16)c.z; pk.h[7] = (_Float16)c.w;
            ((uint4*)xh)[i] = pk.u;
        }
    } else if (b < XB + 320) {
        const float* Ws[6] = {W0, W1, W2, W3, W4, W5};
        _Float16* Ds[6] = {D0, D1, D2, D3, D4, D5};
        int j = (b - XB) * 256 + t;
        int m, jj, kout;
        if (j < 65536) { m = j >> 14; jj = j & 16383; kout = 128; }
        else           { m = 4 + ((j - 65536) >> 13); jj = (j - 65536) & 8191; kout = 64; }
        int col = jj >> 7, k = jj & 127;
        Ds[m][col * 128 + k] = (_Float16)Ws[m][k * kout + col];
    } else {
        int i = (b - XB - 320) * 256 + t;
        if (i < n) deg[i] = 0;
        else if (i < n + npacc) pacc[i - n] = 0.f;
    }
}

// ---------------- CSR build ----------------
// count: atomic return value = edge's rank within its target row
__global__ void k_count(const int* __restrict__ tgt, int* __restrict__ deg,
                        int* __restrict__ rank, int e) {
    int i = blockIdx.x * 256 + threadIdx.x;
    if (i < e) rank[i] = atomicAdd(&deg[tgt[i]], 1);
}
// block scans 4096 elements (256 threads x 16); +1 per element folds in the self-loop
__global__ __launch_bounds__(256) void k_scanA(const int* __restrict__ deg, int* __restrict__ rowptr,
                                               int* __restrict__ bsums, int n) {
    __shared__ int s[256];
    int t = threadIdx.x;
    int base = blockIdx.x * 4096 + t * 16;
    int pre[16];
    int sum = 0;
    for (int i = 0; i < 16; ++i) {
        int idx = base + i;
        int v = (idx < n) ? (deg[idx] + 1) : 0;
        pre[i] = sum;
        sum += v;
    }
    s[t] = sum;
    __syncthreads();
    for (int off = 1; off < 256; off <<= 1) {
        int v = (t >= off) ? s[t - off] : 0;
        __syncthreads();
        s[t] += v;
        __syncthreads();
    }
    int tbase = s[t] - sum;   // exclusive base for this thread within block
    for (int i = 0; i < 16; ++i) {
        int idx = base + i;
        if (idx < n) rowptr[idx] = tbase + pre[i];
    }
    if (t == 0) bsums[blockIdx.x] = s[255];
}
// fused scanB+scanC: per-block prefix of bsums (<=64 entries), finalize rowptr,
// seed self-loop edge at row start, write rowptr[n]
__global__ __launch_bounds__(256) void k_scanC(int* __restrict__ rowptr, const int* __restrict__ bsums,
                                               int* __restrict__ edst, int nscan, int n) {
    __shared__ int pref[65];
    int t = threadIdx.x;
    if (t == 0) {
        int run = 0;
        for (int k = 0; k < nscan; ++k) { pref[k] = run; run += bsums[k]; }
        pref[nscan] = run;
    }
    __syncthreads();
    int i = blockIdx.x * 256 + t;
    if (i < n) {
        int rp = rowptr[i] + pref[i >> 12];   // 4096 per scan block
        rowptr[i] = rp;
        edst[rp] = i;                          // self loop first in each row
    }
    if (blockIdx.x == gridDim.x - 1 && t == 0) rowptr[n] = pref[nscan];
}
// scatter: no atomics; slot = rowptr[tgt] + 1 + rank. nt store avoids L2
// dirty-line ping-pong across the 8 non-coherent XCD L2s.
__global__ void k_scatter(const int* __restrict__ src, const int* __restrict__ tgt,
                          const int* __restrict__ rank, const int* __restrict__ rowptr,
                          int* __restrict__ edst, int e) {
    int i = blockIdx.x * 256 + threadIdx.x;
    if (i < e) {
        int p = rowptr[tgt[i]] + 1 + rank[i];
        __builtin_nontemporal_store(src[i], &edst[p]);
    }
}

// ---------------- MFMA fp16 GEMM: out0 = f16(A@W0), out1 = f16(A@W1) ---------
// A: [n][128] f16. Wt*: [KOUT][128] f16 (transposed weights). No LDS, no barriers.
// KOUT=128: blockIdx.y picks W0->out0 or W1->out1 pass; 8 col-tiles, acc[8]
//   (32 acc VGPRs — leaves room for 8 hoisted B-frag loads in flight per k-step).
// KOUT=64: single pass, ct 0-3 -> W0->out0, ct 4-7 -> W1->out1.
// Frag layouts (verified m89/m91): A[m=lane&15][k=q*8+j], B[k=q*8+j][n=lane&15],
// D: row=q*4+reg, col=lane&15.
template<int KOUT>
__global__ __launch_bounds__(256) void k_gemm_mfma(
        const _Float16* __restrict__ Ah,
        const _Float16* __restrict__ Wt0, const _Float16* __restrict__ Wt1,
        _Float16* __restrict__ out0, _Float16* __restrict__ out1, int n) {
    int wv = threadIdx.x >> 6, lane = threadIdx.x & 63;
    int m = lane & 15, q = lane >> 4;
    int row0 = blockIdx.x * 64 + wv * 16;
    int arow = row0 + m; if (arow >= n) arow = n - 1;
    const _Float16* ap = Ah + (size_t)arow * 128 + q * 8;
    f16x8 af[4];
#pragma unroll
    for (int kt = 0; kt < 4; ++kt) af[kt] = *(const f16x8*)(ap + 32 * kt);

    const _Float16* Wp = Wt0;
    _Float16* outp = out0;
    if (KOUT == 128 && blockIdx.y) { Wp = Wt1; outp = out1; }

    f32x4 acc[8] = {};
#pragma unroll
    for (int kt = 0; kt < 4; ++kt) {
        f16x8 bfr[8];
#pragma unroll
        for (int ct = 0; ct < 8; ++ct) {
            const _Float16* W = (KOUT == 128) ? Wp : (ct < 4 ? Wt0 : Wt1);
            int col0 = (KOUT == 128) ? ct * 16 : (ct & 3) * 16;
            bfr[ct] = *(const f16x8*)(W + (size_t)(col0 + m) * 128 + 32 * kt + 8 * q);
        }
#pragma unroll
        for (int ct = 0; ct < 8; ++ct)
            acc[ct] = __builtin_amdgcn_mfma_f32_16x16x32_f16(af[kt], bfr[ct], acc[ct], 0, 0, 0);
    }
#pragma unroll
    for (int ct = 0; ct < 8; ++ct) {
        _Float16* dst = (KOUT == 128) ? outp : (ct < 4 ? out0 : out1);
        int col = ((KOUT == 128) ? ct * 16 : (ct & 3) * 16) + m;
#pragma unroll
        for (int i = 0; i < 4; ++i) {
            int r = row0 + q * 4 + i;
            if (r < n) dst[(size_t)r * KOUT + col] = (_Float16)acc[ct][i];
        }
    }
}

// ---------------- GATv2 aggregation: 4 nodes per wave, 16 lanes per node ------
// xl AND xr fp16; output OutT (fp16 for layers feeding a GEMM, fp32 for the
// last layer feeding the pool). No max-subtraction (scores bounded ->
// exp(p)/sum exp(p) identical to ref softmax). Edge loop x4.
template<int H, int C, typename OutT>
__global__ __launch_bounds__(256) void k_agg(const __half* __restrict__ xl, const __half* __restrict__ xr,
                                             const float* __restrict__ att, const float* __restrict__ bias,
                                             const int* __restrict__ rowptr, const int* __restrict__ edst,
                                             OutT* __restrict__ yout, int n) {
    constexpr int F = H * C;
    constexpr int VEC = F / 16;      // 8 (F=128) or 4 (F=64)
    constexpr int L = C / VEC;       // lanes per head: 4 or 16
    int lane = threadIdx.x & 63;
    int wave = threadIdx.x >> 6;
    int s = lane & 15;               // sublane within node group
    int node = blockIdx.x * 16 + wave * 4 + (lane >> 4);
    bool valid = node < n;
    int nodeSafe = valid ? node : 0;
    int ch = s * VEC;

    auto loadrow = [&](const __half* base, int row, float* v) {
        const __half* p = base + (size_t)row * F + ch;
        if constexpr (VEC == 8) {
            union { uint4 u4; __half2 h[4]; } pk;
            pk.u4 = *(const uint4*)p;
#pragma unroll
            for (int j = 0; j < 4; ++j) {
                float2 f = __half22float2(pk.h[j]);
                v[2 * j] = f.x; v[2 * j + 1] = f.y;
            }
        } else {
            union { uint2 u2; __half2 h[2]; } pk;
            pk.u2 = *(const uint2*)p;
#pragma unroll
            for (int j = 0; j < 2; ++j) {
                float2 f = __half22float2(pk.h[j]);
                v[2 * j] = f.x; v[2 * j + 1] = f.y;
            }
        }
    };

    float u[VEC], av[VEC], acc[VEC];
    loadrow(xr, nodeSafe, u);
#pragma unroll
    for (int j = 0; j < VEC; ++j) {
        av[j] = att[ch + j];
        acc[j] = 0.f;
    }
    int e0 = rowptr[nodeSafe];
    int deg = valid ? (rowptr[nodeSafe + 1] - e0) : 0;
    int maxdeg = deg;                // wave-uniform max degree over the 4 node groups
    maxdeg = max(maxdeg, __shfl_xor(maxdeg, 16));
    maxdeg = max(maxdeg, __shfl_xor(maxdeg, 32));
    float ssum = 0.f;

    auto dot = [&](const float* v) {
        float p = 0.f;
#pragma unroll
        for (int j = 0; j < VEC; ++j) p += lrelu(v[j] + u[j]) * av[j];
        return p;
    };
    auto accum = [&](float w, const float* v) {
        ssum += w;
#pragma unroll
        for (int j = 0; j < VEC; ++j) acc[j] += w * v[j];
    };

    for (int base = 0; base < maxdeg; base += 16) {
        int cnt = deg - base;                        // group-uniform
        if (cnt > 16) cnt = 16;
        int idxreg = (s < cnt) ? edst[e0 + base + s] : nodeSafe;
        int mcnt = cnt;                              // wave max for this chunk
        mcnt = max(mcnt, __shfl_xor(mcnt, 16));
        mcnt = max(mcnt, __shfl_xor(mcnt, 32));
        int gbase = lane & 48;                       // group<<4
        int i = 0;
        for (; i + 4 <= mcnt; i += 4) {
            int s0 = __shfl(idxreg, gbase + i);
            int s1 = __shfl(idxreg, gbase + i + 1);
            int s2 = __shfl(idxreg, gbase + i + 2);
            int s3 = __shfl(idxreg, gbase + i + 3);
            float v0[VEC], v1[VEC], v2[VEC], v3[VEC];
            loadrow(xl, s0, v0); loadrow(xl, s1, v1);
            loadrow(xl, s2, v2); loadrow(xl, s3, v3);
            float p0 = dot(v0), p1 = dot(v1), p2 = dot(v2), p3 = dot(v3);
#pragma unroll
            for (int off = 1; off < L; off <<= 1) {
                p0 += __shfl_xor(p0, off);
                p1 += __shfl_xor(p1, off);
                p2 += __shfl_xor(p2, off);
                p3 += __shfl_xor(p3, off);
            }
            float w0 = (i + 0 < cnt) ? __expf(p0) : 0.f;
            float w1 = (i + 1 < cnt) ? __expf(p1) : 0.f;
            float w2 = (i + 2 < cnt) ? __expf(p2) : 0.f;
            float w3 = (i + 3 < cnt) ? __expf(p3) : 0.f;
            accum(w0, v0); accum(w1, v1); accum(w2, v2); accum(w3, v3);
        }
        for (; i < mcnt; ++i) {
            int s0 = __shfl(idxreg, gbase + i);
            float v[VEC];
            loadrow(xl, s0, v);
            float p = dot(v);
#pragma unroll
            for (int off = 1; off < L; off <<= 1) p += __shfl_xor(p, off);
            float w = (i < cnt) ? __expf(p) : 0.f;
            accum(w, v);
        }
    }
    if (valid) {
        float inv = 1.f / ssum;
        float o[VEC];
#pragma unroll
        for (int j = 0; j < VEC; ++j) o[j] = lrelu(acc[j] * inv + bias[ch + j]);
        if constexpr (sizeof(OutT) == 2) {
            _Float16* p = (_Float16*)yout + (size_t)node * F + ch;
            if constexpr (VEC == 8) {
                union { uint4 u; _Float16 h[8]; } pk;
#pragma unroll
                for (int j = 0; j < 8; ++j) pk.h[j] = (_Float16)o[j];
                *(uint4*)p = pk.u;
            } else {
                union { uint2 u; _Float16 h[4]; } pk;
#pragma unroll
                for (int j = 0; j < 4; ++j) pk.h[j] = (_Float16)o[j];
                *(uint2*)p = pk.u;
            }
        } else {
            float* p = (float*)yout + (size_t)node * F + ch;
            *(float4*)p = make_float4(o[0], o[1], o[2], o[3]);
            if constexpr (VEC == 8)
                *(float4*)(p + 4) = make_float4(o[4], o[5], o[6], o[7]);
        }
    }
}

// ---------------- hierarchical global mean pool ----------------
__global__ __launch_bounds__(256) void k_pool_partial(const float* __restrict__ y,
        const int* __restrict__ batch, float* __restrict__ pacc, int n, int nchunk) {
    __shared__ float sdata[256];
    __shared__ int range[2];
    int g = blockIdx.x;
    int chunk = blockIdx.y;
    int t = threadIdx.x;
    if (t == 0) {
        int lo = 0, hi = n;
        while (lo < hi) { int mid = (lo + hi) >> 1; if (batch[mid] < g) lo = mid + 1; else hi = mid; }
        range[0] = lo;
        hi = n;
        while (lo < hi) { int mid = (lo + hi) >> 1; if (batch[mid] < g + 1) lo = mid + 1; else hi = mid; }
        range[1] = lo;
    }
    __syncthreads();
    int start = range[0], len = range[1] - range[0];
    int lo = start + (int)((long long)len * chunk / nchunk);
    int hi = start + (int)((long long)len * (chunk + 1) / nchunk);
    int ch = t & 63, sub = t >> 6;
    float acc = 0.f;
    for (int node = lo + sub; node < hi; node += 4)
        acc += y[(size_t)node * 64 + ch];
    sdata[t] = acc;
    __syncthreads();
    if (t < 128) sdata[t] += sdata[t + 128];
    __syncthreads();
    if (t < 64) atomicAdd(&pacc[g * 64 + t], sdata[t] + sdata[t + 64]);
}
__global__ void k_pool_final(const float* __restrict__ pacc, const int* __restrict__ batch,
                             float* __restrict__ out, int n) {
    __shared__ int cntS;
    int g = blockIdx.x, t = threadIdx.x;
    if (t == 0) {
        int lo = 0, hi = n;
        while (lo < hi) { int mid = (lo + hi) >> 1; if (batch[mid] < g) lo = mid + 1; else hi = mid; }
        int s = lo;
        hi = n;
        while (lo < hi) { int mid = (lo + hi) >> 1; if (batch[mid] < g + 1) lo = mid + 1; else hi = mid; }
        cntS = lo - s;
    }
    __syncthreads();
    out[g * 64 + t] = pacc[g * 64 + t] / fmaxf((float)cntS, 1.f);
}

extern "C" void kernel_launch(void* const* d_in, const int* in_sizes, int n_in,
                              void* d_out, int out_size, void* d_ws, size_t ws_size,
                              hipStream_t stream) {
    const float* x     = (const float*)d_in[0];
    const int*   ei    = (const int*)d_in[1];
    const int*   batch = (const int*)d_in[2];
    const float* Wl0 = (const float*)d_in[3];
    const float* Wr0 = (const float*)d_in[4];
    const float* att0 = (const float*)d_in[5];
    const float* b0  = (const float*)d_in[6];
    const float* Wl1 = (const float*)d_in[7];
    const float* Wr1 = (const float*)d_in[8];
    const float* att1 = (const float*)d_in[9];
    const float* b1  = (const float*)d_in[10];
    const float* Wl2 = (const float*)d_in[11];
    const float* Wr2 = (const float*)d_in[12];
    const float* att2 = (const float*)d_in[13];
    const float* b2  = (const float*)d_in[14];

    const int N = in_sizes[2];        // 50000
    const int E = in_sizes[1] / 2;    // 800000
    const int G = out_size / 64;      // 64
    const int* src = ei;
    const int* tgt = ei + E;

    // workspace layout (all 256B aligned)
    size_t off = 0;
    auto take = [&](size_t bytes) {
        void* p = (char*)d_ws + off;
        off = (off + bytes + 255) & ~(size_t)255;
        return p;
    };
    _Float16* xh   = (_Float16*)take((size_t)N * 128 * 2); // x in fp16
    _Float16* Ah   = (_Float16*)take((size_t)N * 128 * 2); // xl (f16, gather payload)
    _Float16* B    = (_Float16*)take((size_t)N * 128 * 2); // xr (f16)
    _Float16* Cbh  = (_Float16*)take((size_t)N * 128 * 2); // agg out layers 0/1 (f16)
    float* Cbf     = (float*)take((size_t)N * 64 * 4);     // agg out layer 2 (f32)
    _Float16* Wl0t = (_Float16*)take(128 * 128 * 2);
    _Float16* Wr0t = (_Float16*)take(128 * 128 * 2);
    _Float16* Wl1t = (_Float16*)take(128 * 128 * 2);
    _Float16* Wr1t = (_Float16*)take(128 * 128 * 2);
    _Float16* Wl2t = (_Float16*)take(64 * 128 * 2);
    _Float16* Wr2t = (_Float16*)take(64 * 128 * 2);
    int* rowptr = (int*)take((size_t)(N + 1) * 4);
    int* tmp    = (int*)take((size_t)N * 4);          // deg (zeroed in k_prep)
    float* pacc = (float*)take((size_t)G * 64 * 4);   // pool acc (zeroed in k_prep)
    int* rank   = (int*)take((size_t)E * 4);          // edge rank within target row
    int* edst   = (int*)take((size_t)(E + N) * 4);
    int* bsums  = (int*)take(64 * 4);
    (void)ws_size; (void)n_in;

    const int TB = 256;
    int nblkN = (N + TB - 1) / TB;
    int nblkE = (E + TB - 1) / TB;
    int nscan = (N + 4095) / 4096;

    // --- prep: zeroing + fp16 conversions (one launch) ---
    int n8 = N * 128 / 8;
    int XB = (n8 + TB - 1) / TB;
    int ZB = (N + G * 64 + TB - 1) / TB;
    k_prep<<<XB + 320 + ZB, TB, 0, stream>>>(x, xh, n8, XB,
        Wl0, Wr0, Wl1, Wr1, Wl2, Wr2,
        Wl0t, Wr0t, Wl1t, Wr1t, Wl2t, Wr2t,
        tmp, pacc, N, G * 64);

    // --- CSR build: count(+rank), scan, seed self-loops, atomic-free scatter ---
    k_count<<<nblkE, TB, 0, stream>>>(tgt, tmp, rank, E);
    k_scanA<<<nscan, TB, 0, stream>>>(tmp, rowptr, bsums, N);
    k_scanC<<<nblkN, TB, 0, stream>>>(rowptr, bsums, edst, nscan, N);
    k_scatter<<<nblkE, TB, 0, stream>>>(src, tgt, rank, rowptr, edst, E);

    int gemmBlocks = (N + 63) / 64;
    dim3 gemmGrid2(gemmBlocks, 2);    // KOUT=128: W0/W1 passes split across y
    dim3 gemmGrid1(gemmBlocks, 1);    // KOUT=64: merged single pass
    int aggBlocks = (N + 15) / 16;

    // --- layer 0 ---
    k_gemm_mfma<128><<<gemmGrid2, TB, 0, stream>>>(xh, Wl0t, Wr0t, Ah, B, N);
    k_agg<4, 32, _Float16><<<aggBlocks, TB, 0, stream>>>((const __half*)Ah, (const __half*)B, att0, b0, rowptr, edst, Cbh, N);

    // --- layer 1 ---
    k_gemm_mfma<128><<<gemmGrid2, TB, 0, stream>>>(Cbh, Wl1t, Wr1t, Ah, B, N);
    k_agg<4, 32, _Float16><<<aggBlocks, TB, 0, stream>>>((const __half*)Ah, (const __half*)B, att1, b1, rowptr, edst, Cbh, N);

    // --- layer 2 ---
    k_gemm_mfma<64><<<gemmGrid1, TB, 0, stream>>>(Cbh, Wl2t, Wr2t, Ah, B, N);
    k_agg<1, 64, float><<<aggBlocks, TB, 0, stream>>>((const __half*)Ah, (const __half*)B, att2, b2, rowptr, edst, Cbf, N);

    // --- hierarchical global mean pool ---
    dim3 poolGrid(G, 16);
    k_pool_partial<<<poolGrid, TB, 0, stream>>>(Cbf, batch, pacc, N, 16);
    k_pool_final<<<G, 64, 0, stream>>>(pacc, batch, (float*)d_out, N);
}